// Round 7
// baseline (292.532 us; speedup 1.0000x reference)
//
#include <hip/hip_runtime.h>
#include <hip/hip_bf16.h>

#define NROW 4096
#define D0   1024
#define DH1  512
#define DH2  256
#define DLAT 128
#define SLOPE 0.01f

typedef float f32x4 __attribute__((ext_vector_type(4)));
typedef __bf16 bf16x8 __attribute__((ext_vector_type(8)));
typedef short short8 __attribute__((ext_vector_type(8)));

#define WAITV(N) asm volatile("s_waitcnt vmcnt(" #N ")" ::: "memory")
#define BARRIER() do { __builtin_amdgcn_s_barrier(); __builtin_amdgcn_sched_barrier(0); } while (0)

// ---- async global->LDS 16B (wave-uniform base + lane*16 dest) ----
__device__ __forceinline__ void gload_lds16(const void* gp, void* lp) {
    __builtin_amdgcn_global_load_lds(
        (const __attribute__((address_space(1))) void*)(unsigned long long)gp,
        (__attribute__((address_space(3))) void*)(unsigned int)(unsigned long long)lp,
        16, 0, 0);
}

__device__ __forceinline__ bf16x8 ldfrag(const short* p) {
    union { short8 s; bf16x8 b; } u;
    u.s = *reinterpret_cast<const short8*>(p);
    return u.b;
}

__device__ __forceinline__ unsigned packbf2(float a, float b) {
    union { __hip_bfloat16 h; unsigned short u; } ua, ub;
    ua.h = __float2bfloat16(a); ub.h = __float2bfloat16(b);
    return (unsigned)ua.u | ((unsigned)ub.u << 16);
}
__device__ __forceinline__ float unpackbf(unsigned p, int hi) {
    union { unsigned short u; __hip_bfloat16 h; } t;
    t.u = (unsigned short)(hi ? (p >> 16) : p);
    return __bfloat162float(t.h);
}

#define MFMA16(A, B, C) __builtin_amdgcn_mfma_f32_16x16x32_bf16((A), (B), (C), 0, 0, 0)

// ---- split-precision GEMM: C = lrelu(A @ W^T + b), BM=128 BN=64 ----
// Depth-3 counted-vmcnt pipeline (3 LDS buffer sets, WAITV(6) steady state).
// 3-MFMA split: ah*bh + ah*bl + al*bh (residual ~2^-18 relative).
__global__ __launch_bounds__(256, 2) void gemm_lrelu(
    const __hip_bfloat16* __restrict__ Ah, const __hip_bfloat16* __restrict__ Al,
    const __hip_bfloat16* __restrict__ Wh, const __hip_bfloat16* __restrict__ Wl,
    const float* __restrict__ bias,
    float* __restrict__ Cf, __hip_bfloat16* __restrict__ Ch, __hip_bfloat16* __restrict__ Cl,
    float* __restrict__ sumsq, int N, int K)
{
    __shared__ short smem[36864];
    const int tid = threadIdx.x, lane = tid & 63, wave = tid >> 6;
    const int wm = wave >> 1, wn = wave & 1;
    const int bm = blockIdx.x, bn = blockIdx.y;
    const int nk = K >> 5;

    const int lr0 = wave * 32 + (lane >> 2), lr1 = lr0 + 16;
    const int lrW = wave * 16 + (lane >> 2);
    const int ts  = lane & 3;
    const int sa  = ts ^ ((lr0 >> 1) & 3);
    const int sw  = ts ^ ((lrW >> 1) & 3);

    const __hip_bfloat16* pAh0 = Ah + (size_t)(bm * 128 + lr0) * K + sa * 8;
    const __hip_bfloat16* pAh1 = Ah + (size_t)(bm * 128 + lr1) * K + sa * 8;
    const __hip_bfloat16* pAl0 = Al + (size_t)(bm * 128 + lr0) * K + sa * 8;
    const __hip_bfloat16* pAl1 = Al + (size_t)(bm * 128 + lr1) * K + sa * 8;
    const __hip_bfloat16* pWh0 = Wh + (size_t)(bn * 64 + lrW) * K + sw * 8;
    const __hip_bfloat16* pWl0 = Wl + (size_t)(bn * 64 + lrW) * K + sw * 8;

    short* dAh0 = smem + lr0 * 32 + ts * 8;
    short* dAh1 = smem + lr1 * 32 + ts * 8;
    short* dAl0 = smem + 12288 + lr0 * 32 + ts * 8;
    short* dAl1 = smem + 12288 + lr1 * 32 + ts * 8;
    short* dWh  = smem + 24576 + lrW * 32 + ts * 8;
    short* dWl  = smem + 30720 + lrW * 32 + ts * 8;

    const int rA = wm * 64 + (lane & 15);
    const int rB = wn * 32 + (lane & 15);
    const int pos = (lane >> 4) ^ ((lane >> 1) & 3);
    const short* baseA = smem + rA * 32 + pos * 8;            // Ah; Al at +12288
    const short* baseB = smem + 24576 + rB * 32 + pos * 8;    // Wh; Wl at +6144

    f32x4 acc[4][2] = {};

    auto STAGE = [&](int oA) {   // 6 gloads; oW = oA>>1
        int oW = oA >> 1;
        gload_lds16(pAh0, dAh0 + oA); gload_lds16(pAh1, dAh1 + oA);
        gload_lds16(pAl0, dAl0 + oA); gload_lds16(pAl1, dAl1 + oA);
        gload_lds16(pWh0, dWh + oW);  gload_lds16(pWl0, dWl + oW);
        pAh0 += 32; pAh1 += 32; pAl0 += 32; pAl1 += 32; pWh0 += 32; pWl0 += 32;
    };
    auto STEP = [&](int oA) {
        int oW = oA >> 1;
        bf16x8 ah[4], al[4], bh[2], bl[2];
#pragma unroll
        for (int m = 0; m < 4; ++m) {
            ah[m] = ldfrag(baseA + oA + m * 512);
            al[m] = ldfrag(baseA + 12288 + oA + m * 512);
        }
#pragma unroll
        for (int n = 0; n < 2; ++n) {
            bh[n] = ldfrag(baseB + oW + n * 512);
            bl[n] = ldfrag(baseB + 6144 + oW + n * 512);
        }
#pragma unroll
        for (int m = 0; m < 4; ++m)
#pragma unroll
            for (int n = 0; n < 2; ++n) {
                acc[m][n] = MFMA16(ah[m], bh[n], acc[m][n]);
                acc[m][n] = MFMA16(ah[m], bl[n], acc[m][n]);
                acc[m][n] = MFMA16(al[m], bh[n], acc[m][n]);
            }
    };

    STAGE(0); STAGE(4096);
    int oc = 0;
#pragma unroll 1
    for (int k = 0; k < nk - 1; ++k) {
        WAITV(6);
        BARRIER();
        int o2 = (oc == 0) ? 8192 : oc - 4096;
        if (k + 2 < nk) STAGE(o2);
        STEP(oc);
        oc = (oc == 8192) ? 0 : oc + 4096;
    }
    WAITV(0); BARRIER();
    STEP(oc);

    float bcol[2];
#pragma unroll
    for (int n = 0; n < 2; ++n) bcol[n] = bias[bn * 64 + wn * 32 + n * 16 + (lane & 15)];

#pragma unroll
    for (int m = 0; m < 4; ++m)
#pragma unroll
        for (int n = 0; n < 2; ++n)
#pragma unroll
            for (int j = 0; j < 4; ++j) {
                float v = acc[m][n][j] + bcol[n];
                acc[m][n][j] = v >= 0.f ? v : SLOPE * v;
            }
#pragma unroll
    for (int m = 0; m < 4; ++m)
#pragma unroll
        for (int n = 0; n < 2; ++n)
#pragma unroll
            for (int j = 0; j < 4; ++j) {
                int grow = bm * 128 + wm * 64 + m * 16 + (lane >> 4) * 4 + j;
                int gcol = bn * 64 + wn * 32 + n * 16 + (lane & 15);
                size_t idx = (size_t)grow * N + gcol;
                float v = acc[m][n][j];
                if (Cf) Cf[idx] = v;
                if (Ch) {
                    __hip_bfloat16 h = __float2bfloat16(v);
                    Ch[idx] = h;
                    Cl[idx] = __float2bfloat16(v - __bfloat162float(h));
                }
            }
    if (sumsq) {
#pragma unroll
        for (int m = 0; m < 4; ++m)
#pragma unroll
            for (int j = 0; j < 4; ++j) {
                float p = acc[m][0][j] * acc[m][0][j] + acc[m][1][j] * acc[m][1][j];
#pragma unroll
                for (int w = 1; w < 16; w <<= 1) p += __shfl_xor(p, w);
                if ((lane & 15) == 0) {
                    int grow = bm * 128 + wm * 64 + m * 16 + (lane >> 4) * 4 + j;
                    atomicAdd(&sumsq[grow], p);
                }
            }
    }
}

// ---- fused pairwise-distance statistics: m97 geometry (4 waves, 64x64/wave) ----
// Latent phase FIRST (4 steps, acc2[4][4]) -> convert to d2, fold s2/s22 in f32,
// pack d2 to bf16 pairs (32 VGPR). X phase (32 steps, acc[4][4]). 3 LDS buffer
// sets, depth-2-ahead, WAITV(4) steady. Full square grid 1024 blocks (XCD swz).
__global__ __launch_bounds__(256) void pairwise_corr(
    const __hip_bfloat16* __restrict__ Xh, const __hip_bfloat16* __restrict__ Lh,
    const float* __restrict__ r1, const float* __restrict__ r2,
    double* __restrict__ stats)
{
    int bid = (blockIdx.x & 7) * 128 + (blockIdx.x >> 3);   // 1024 = 8*128 bijective
    const int bm = bid >> 5, bn = bid & 31;

    __shared__ short smem[24576];   // A@{0,4096,8192}, B@12288+{0,4096,8192}
    const int tid = threadIdx.x, lane = tid & 63, wave = tid >> 6;
    const int wm = wave >> 1, wn = wave & 1;

    const int lr0 = wave * 32 + (lane >> 2), lr1 = lr0 + 16;
    const int ts = lane & 3;
    const int sa = ts ^ ((lr0 >> 1) & 3);

    const __hip_bfloat16* pXa0 = Xh + (size_t)(bm * 128 + lr0) * D0 + sa * 8;
    const __hip_bfloat16* pXa1 = Xh + (size_t)(bm * 128 + lr1) * D0 + sa * 8;
    const __hip_bfloat16* pXb0 = Xh + (size_t)(bn * 128 + lr0) * D0 + sa * 8;
    const __hip_bfloat16* pXb1 = Xh + (size_t)(bn * 128 + lr1) * D0 + sa * 8;
    const __hip_bfloat16* qLa0 = Lh + (size_t)(bm * 128 + lr0) * DLAT + sa * 8;
    const __hip_bfloat16* qLa1 = Lh + (size_t)(bm * 128 + lr1) * DLAT + sa * 8;
    const __hip_bfloat16* qLb0 = Lh + (size_t)(bn * 128 + lr0) * DLAT + sa * 8;
    const __hip_bfloat16* qLb1 = Lh + (size_t)(bn * 128 + lr1) * DLAT + sa * 8;

    short* dA0 = smem + lr0 * 32 + ts * 8;
    short* dA1 = smem + lr1 * 32 + ts * 8;
    short* dB0 = smem + 12288 + lr0 * 32 + ts * 8;
    short* dB1 = smem + 12288 + lr1 * 32 + ts * 8;

    const int pos = (lane >> 4) ^ ((lane >> 1) & 3);
    const short* baseA = smem + (wm * 64 + (lane & 15)) * 32 + pos * 8;
    const short* baseB = smem + 12288 + (wn * 64 + (lane & 15)) * 32 + pos * 8;

    auto STAGEX = [&](int o) {   // 4 gloads per wave
        gload_lds16(pXa0, dA0 + o); gload_lds16(pXa1, dA1 + o);
        gload_lds16(pXb0, dB0 + o); gload_lds16(pXb1, dB1 + o);
        pXa0 += 32; pXa1 += 32; pXb0 += 32; pXb1 += 32;
    };
    auto STAGEL = [&](int o) {
        gload_lds16(qLa0, dA0 + o); gload_lds16(qLa1, dA1 + o);
        gload_lds16(qLb0, dB0 + o); gload_lds16(qLb1, dB1 + o);
        qLa0 += 32; qLa1 += 32; qLb0 += 32; qLb1 += 32;
    };

    f32x4 acc2[4][4] = {};
    auto STEP = [&](int o, f32x4 (&A)[4][4]) {
        bf16x8 a[4], b[4];
#pragma unroll
        for (int m = 0; m < 4; ++m) a[m] = ldfrag(baseA + o + m * 512);
#pragma unroll
        for (int n = 0; n < 4; ++n) b[n] = ldfrag(baseB + o + n * 512);
#pragma unroll
        for (int m = 0; m < 4; ++m)
#pragma unroll
            for (int n = 0; n < 4; ++n)
                A[m][n] = MFMA16(a[m], b[n], A[m][n]);
    };

    // prologue: r2 row norms (needed at phase transition; L2-hot, lands early)
    float r2i[4][4], r2j[4];
#pragma unroll
    for (int m = 0; m < 4; ++m)
#pragma unroll
        for (int j = 0; j < 4; ++j)
            r2i[m][j] = r2[bm * 128 + wm * 64 + m * 16 + (lane >> 4) * 4 + j];
#pragma unroll
    for (int n = 0; n < 4; ++n)
        r2j[n] = r2[bn * 128 + wn * 64 + n * 16 + (lane & 15)];

    STAGEL(0); STAGEL(4096);
    WAITV(4); BARRIER(); STAGEL(8192); STEP(0, acc2);      // c=L0, stage L2
    WAITV(4); BARRIER(); STAGEL(0);    STEP(4096, acc2);   // c=L1, stage L3
    WAITV(4); BARRIER(); STAGEX(4096); STEP(8192, acc2);   // c=L2, stage X0->buf1
    WAITV(4); BARRIER(); STAGEX(8192); STEP(0, acc2);      // c=L3, stage X1->buf2

    // --- phase transition: latent Gram -> distances; fold s2/s22; pack d2 ---
    float s2 = 0.f, s22 = 0.f;
    unsigned d2p[4][4][2];
#pragma unroll
    for (int m = 0; m < 4; ++m)
#pragma unroll
        for (int n = 0; n < 4; ++n)
#pragma unroll
            for (int jj = 0; jj < 2; ++jj) {
                float dv[2];
#pragma unroll
                for (int h = 0; h < 2; ++h) {
                    int j = jj * 2 + h;
                    int gi = bm * 128 + wm * 64 + m * 16 + (lane >> 4) * 4 + j;
                    int gj = bn * 128 + wn * 64 + n * 16 + (lane & 15);
                    float sq = r2i[m][j] + r2j[n] - 2.0f * acc2[m][n][j];
                    dv[h] = (gi == gj || sq <= 0.f) ? 0.f : sqrtf(sq);
                    s2 += dv[h]; s22 += dv[h] * dv[h];
                }
                d2p[m][n][jj] = packbf2(dv[0], dv[1]);
            }

    f32x4 acc[4][4];
#pragma unroll
    for (int m = 0; m < 4; ++m)
#pragma unroll
        for (int n = 0; n < 4; ++n)
#pragma unroll
            for (int j = 0; j < 4; ++j) acc[m][n][j] = 0.f;

    WAITV(4); BARRIER(); STAGEX(0);    STEP(4096, acc);    // c=X0, stage X2->buf0
    WAITV(4); BARRIER(); STAGEX(4096); STEP(8192, acc);    // c=X1, stage X3->buf1
#pragma unroll 1
    for (int k = 0; k < 9; ++k) {                          // c=X2..X28
        WAITV(4); BARRIER(); STAGEX(8192); STEP(0, acc);
        WAITV(4); BARRIER(); STAGEX(0);    STEP(4096, acc);
        WAITV(4); BARRIER(); STAGEX(4096); STEP(8192, acc);
    }
    WAITV(4); BARRIER(); STAGEX(8192); STEP(0, acc);       // c=X29, stage X31
    WAITV(4); BARRIER();               STEP(4096, acc);    // c=X30
    WAITV(0); BARRIER();               STEP(8192, acc);    // c=X31

    // --- final epilogue: d1 distances + 5 stats ---
    float r1i[4][4], r1j[4];
#pragma unroll
    for (int m = 0; m < 4; ++m)
#pragma unroll
        for (int j = 0; j < 4; ++j)
            r1i[m][j] = r1[bm * 128 + wm * 64 + m * 16 + (lane >> 4) * 4 + j];
#pragma unroll
    for (int n = 0; n < 4; ++n)
        r1j[n] = r1[bn * 128 + wn * 64 + n * 16 + (lane & 15)];

    float s1 = 0.f, s11 = 0.f, s12 = 0.f;
#pragma unroll
    for (int m = 0; m < 4; ++m)
#pragma unroll
        for (int n = 0; n < 4; ++n)
#pragma unroll
            for (int j = 0; j < 4; ++j) {
                int gi = bm * 128 + wm * 64 + m * 16 + (lane >> 4) * 4 + j;
                int gj = bn * 128 + wn * 64 + n * 16 + (lane & 15);
                float sq1 = r1i[m][j] + r1j[n] - 2.0f * acc[m][n][j];
                float d1v = (gi == gj || sq1 <= 0.f) ? 0.f : sqrtf(sq1);
                float d2v = unpackbf(d2p[m][n][j >> 1], j & 1);
                s1 += d1v; s11 += d1v * d1v; s12 += d1v * d2v;
            }

    float vals[5] = { s1, s2, s11, s22, s12 };
#pragma unroll
    for (int q = 0; q < 5; ++q)
        for (int off = 32; off; off >>= 1) vals[q] += __shfl_down(vals[q], off);

    __syncthreads();                 // done with LDS; reuse as reduce buffer
    float* red = (float*)smem;
    if (lane == 0) {
#pragma unroll
        for (int q = 0; q < 5; ++q) red[wave * 5 + q] = vals[q];
    }
    __syncthreads();
    if (tid == 0) {
#pragma unroll
        for (int q = 0; q < 5; ++q) {
            double tt = (double)red[q] + (double)red[5 + q] + (double)red[10 + q] + (double)red[15 + q];
            atomicAdd(&stats[q], tt);
        }
    }
}

// ---- fused hi/lo split for x + all 6 weights; also r1 = rowsumsq(x) ----
struct SplitSeg { const float* src; __hip_bfloat16* hi; __hip_bfloat16* lo; };
struct SplitArgs { SplitSeg s[7]; unsigned cum4[8]; };

__global__ void split_many(SplitArgs A, int total4, float* __restrict__ r1) {
    int v = blockIdx.x * blockDim.x + threadIdx.x;
    if (v >= total4) return;
    int si = 0;
#pragma unroll
    for (int i = 1; i < 7; ++i) si = (v >= (int)A.cum4[i]) ? i : si;
    int local = v - (int)A.cum4[si];
    float4 f = *(const float4*)(A.s[si].src + (size_t)local * 4);
    float fv[4] = { f.x, f.y, f.z, f.w };
    __hip_bfloat16* hi = A.s[si].hi;
    __hip_bfloat16* lo = A.s[si].lo;
#pragma unroll
    for (int j = 0; j < 4; ++j) {
        __hip_bfloat16 h = __float2bfloat16(fv[j]);
        hi[local * 4 + j] = h;
        lo[local * 4 + j] = __float2bfloat16(fv[j] - __bfloat162float(h));
    }
    if (blockIdx.x < 4096) {   // pure-x block == one row of x
        float s = fv[0]*fv[0] + fv[1]*fv[1] + fv[2]*fv[2] + fv[3]*fv[3];
        for (int off = 32; off; off >>= 1) s += __shfl_down(s, off);
        __shared__ float red[4];
        int lane = threadIdx.x & 63, wave = threadIdx.x >> 6;
        if (lane == 0) red[wave] = s;
        __syncthreads();
        if (threadIdx.x == 0) r1[blockIdx.x] = red[0] + red[1] + red[2] + red[3];
    }
}

__global__ void finalize_corr(const double* __restrict__ stats, float* __restrict__ corr_out) {
    double n = (double)NROW * (double)NROW;
    double s1 = stats[0], s2 = stats[1], s11 = stats[2], s22 = stats[3], s12 = stats[4];
    double m1 = s1 / n, m2 = s2 / n;
    double cov = s12 / n - m1 * m2;                  // biased (mean)
    double v1 = (s11 - n * m1 * m1) / (n - 1.0);     // unbiased (ddof=1)
    double v2 = (s22 - n * m2 * m2) / (n - 1.0);
    corr_out[0] = (float)(cov / sqrt(v1 * v2));
}

extern "C" void kernel_launch(void* const* d_in, const int* in_sizes, int n_in,
                              void* d_out, int out_size, void* d_ws, size_t ws_size,
                              hipStream_t stream) {
    const float* x   = (const float*)d_in[0];
    const float* We1 = (const float*)d_in[1];  const float* be1 = (const float*)d_in[2];
    const float* We2 = (const float*)d_in[3];  const float* be2 = (const float*)d_in[4];
    const float* We3 = (const float*)d_in[5];  const float* be3 = (const float*)d_in[6];
    const float* Wd1 = (const float*)d_in[7];  const float* bd1 = (const float*)d_in[8];
    const float* Wd2 = (const float*)d_in[9];  const float* bd2 = (const float*)d_in[10];
    const float* Wd3 = (const float*)d_in[11]; const float* bd3 = (const float*)d_in[12];
    float* out = (float*)d_out;

    char* ws = (char*)d_ws;
    size_t off = 0;
    auto alloc = [&](size_t bytes) -> char* {
        char* p = ws + off; off += (bytes + 255) & ~(size_t)255; return p;
    };
    typedef __hip_bfloat16 bf;
    bf* xh  = (bf*)alloc((size_t)NROW * D0 * 2);   bf* xl  = (bf*)alloc((size_t)NROW * D0 * 2);
    bf* w1h = (bf*)alloc((size_t)DH1 * D0 * 2);    bf* w1l = (bf*)alloc((size_t)DH1 * D0 * 2);
    bf* w2h = (bf*)alloc((size_t)DH2 * DH1 * 2);   bf* w2l = (bf*)alloc((size_t)DH2 * DH1 * 2);
    bf* w3h = (bf*)alloc((size_t)DLAT * DH2 * 2);  bf* w3l = (bf*)alloc((size_t)DLAT * DH2 * 2);
    bf* w4h = (bf*)alloc((size_t)DH2 * DLAT * 2);  bf* w4l = (bf*)alloc((size_t)DH2 * DLAT * 2);
    bf* w5h = (bf*)alloc((size_t)DH1 * DH2 * 2);   bf* w5l = (bf*)alloc((size_t)DH1 * DH2 * 2);
    bf* w6h = (bf*)alloc((size_t)D0 * DH1 * 2);    bf* w6l = (bf*)alloc((size_t)D0 * DH1 * 2);
    bf* h1h = (bf*)alloc((size_t)NROW * DH1 * 2);  bf* h1l = (bf*)alloc((size_t)NROW * DH1 * 2);
    bf* h2h = (bf*)alloc((size_t)NROW * DH2 * 2);  bf* h2l = (bf*)alloc((size_t)NROW * DH2 * 2);
    bf* lth = (bf*)alloc((size_t)NROW * DLAT * 2); bf* ltl = (bf*)alloc((size_t)NROW * DLAT * 2);
    bf* d4h = (bf*)alloc((size_t)NROW * DH2 * 2);  bf* d4l = (bf*)alloc((size_t)NROW * DH2 * 2);
    bf* d5h = (bf*)alloc((size_t)NROW * DH1 * 2);  bf* d5l = (bf*)alloc((size_t)NROW * DH1 * 2);
    float* r1v = (float*)alloc((size_t)NROW * 4);
    float* r2v = (float*)alloc((size_t)NROW * 4);      // 16384 B, 256-aligned
    double* stats = (double*)alloc(5 * 8);             // contiguous after r2v

    // zero r2v + stats in one async memset (graph-capture safe)
    hipMemsetAsync(r2v, 0, (size_t)NROW * 4 + 256, stream);

    SplitArgs SA;
    const float* srcs[7] = { x, We1, We2, We3, Wd1, Wd2, Wd3 };
    bf* his[7] = { xh, w1h, w2h, w3h, w4h, w5h, w6h };
    bf* los[7] = { xl, w1l, w2l, w3l, w4l, w5l, w6l };
    unsigned ns[7] = { NROW * D0, DH1 * D0, DH2 * DH1, DLAT * DH2,
                       DH2 * DLAT, DH1 * DH2, D0 * DH1 };
    unsigned cum = 0;
    for (int i = 0; i < 7; ++i) {
        SA.s[i].src = srcs[i]; SA.s[i].hi = his[i]; SA.s[i].lo = los[i];
        SA.cum4[i] = cum; cum += ns[i] / 4;
    }
    SA.cum4[7] = cum;
    split_many<<<(cum + 255) / 256, 256, 0, stream>>>(SA, (int)cum, r1v);

    // encoder
    gemm_lrelu<<<dim3(NROW / 128, DH1 / 64), 256, 0, stream>>>(
        xh, xl, w1h, w1l, be1, nullptr, h1h, h1l, nullptr, DH1, D0);
    gemm_lrelu<<<dim3(NROW / 128, DH2 / 64), 256, 0, stream>>>(
        h1h, h1l, w2h, w2l, be2, nullptr, h2h, h2l, nullptr, DH2, DH1);
    gemm_lrelu<<<dim3(NROW / 128, DLAT / 64), 256, 0, stream>>>(
        h2h, h2l, w3h, w3l, be3, nullptr, lth, ltl, r2v, DLAT, DH2);
    // decoder
    gemm_lrelu<<<dim3(NROW / 128, DH2 / 64), 256, 0, stream>>>(
        lth, ltl, w4h, w4l, bd1, nullptr, d4h, d4l, nullptr, DH2, DLAT);
    gemm_lrelu<<<dim3(NROW / 128, DH1 / 64), 256, 0, stream>>>(
        d4h, d4l, w5h, w5l, bd2, nullptr, d5h, d5l, nullptr, DH1, DH2);
    gemm_lrelu<<<dim3(NROW / 128, D0 / 64), 256, 0, stream>>>(
        d5h, d5l, w6h, w6l, bd3, out, nullptr, nullptr, nullptr, D0, DH1);

    // fused pairwise-distance correlation statistics (full square: 1024 blocks)
    pairwise_corr<<<dim3(1024), 256, 0, stream>>>(xh, lth, r1v, r2v, stats);
    finalize_corr<<<1, 1, 0, stream>>>(stats, out + (size_t)NROW * D0);
}

// Round 8
// 254.508 us; speedup vs baseline: 1.1494x; 1.1494x over previous
//
#include <hip/hip_runtime.h>
#include <hip/hip_bf16.h>

#define NROW 4096
#define D0   1024
#define DH1  512
#define DH2  256
#define DLAT 128
#define SLOPE 0.01f

typedef float f32x4 __attribute__((ext_vector_type(4)));
typedef __bf16 bf16x8 __attribute__((ext_vector_type(8)));
typedef short short8 __attribute__((ext_vector_type(8)));

#define WAITV(N) asm volatile("s_waitcnt vmcnt(" #N ")" ::: "memory")
#define BARRIER() do { __builtin_amdgcn_s_barrier(); __builtin_amdgcn_sched_barrier(0); } while (0)

// ---- async global->LDS 16B (wave-uniform base + lane*16 dest) ----
__device__ __forceinline__ void gload_lds16(const void* gp, void* lp) {
    __builtin_amdgcn_global_load_lds(
        (const __attribute__((address_space(1))) void*)(unsigned long long)gp,
        (__attribute__((address_space(3))) void*)(unsigned int)(unsigned long long)lp,
        16, 0, 0);
}

__device__ __forceinline__ bf16x8 ldfrag(const short* p) {
    union { short8 s; bf16x8 b; } u;
    u.s = *reinterpret_cast<const short8*>(p);
    return u.b;
}

__device__ __forceinline__ unsigned packbf2(float a, float b) {
    union { __hip_bfloat16 h; unsigned short u; } ua, ub;
    ua.h = __float2bfloat16(a); ub.h = __float2bfloat16(b);
    return (unsigned)ua.u | ((unsigned)ub.u << 16);
}
__device__ __forceinline__ float unpackbf(unsigned p, int hi) {
    union { unsigned short u; __hip_bfloat16 h; } t;
    t.u = (unsigned short)(hi ? (p >> 16) : p);
    return __bfloat162float(t.h);
}

#define MFMA16(A, B, C) __builtin_amdgcn_mfma_f32_16x16x32_bf16((A), (B), (C), 0, 0, 0)

// ---- split-precision GEMM: C = lrelu(A @ W^T + b), BM=128 BN=64 ----
// Depth-3 counted-vmcnt pipeline (3 LDS buffer sets, WAITV(6) steady state).
// 3-MFMA split: ah*bh + ah*bl + al*bh (residual ~2^-18 relative).
__global__ __launch_bounds__(256, 2) void gemm_lrelu(
    const __hip_bfloat16* __restrict__ Ah, const __hip_bfloat16* __restrict__ Al,
    const __hip_bfloat16* __restrict__ Wh, const __hip_bfloat16* __restrict__ Wl,
    const float* __restrict__ bias,
    float* __restrict__ Cf, __hip_bfloat16* __restrict__ Ch, __hip_bfloat16* __restrict__ Cl,
    float* __restrict__ sumsq, int N, int K)
{
    __shared__ short smem[36864];
    const int tid = threadIdx.x, lane = tid & 63, wave = tid >> 6;
    const int wm = wave >> 1, wn = wave & 1;
    const int bm = blockIdx.x, bn = blockIdx.y;
    const int nk = K >> 5;

    const int lr0 = wave * 32 + (lane >> 2), lr1 = lr0 + 16;
    const int lrW = wave * 16 + (lane >> 2);
    const int ts  = lane & 3;
    const int sa  = ts ^ ((lr0 >> 1) & 3);
    const int sw  = ts ^ ((lrW >> 1) & 3);

    const __hip_bfloat16* pAh0 = Ah + (size_t)(bm * 128 + lr0) * K + sa * 8;
    const __hip_bfloat16* pAh1 = Ah + (size_t)(bm * 128 + lr1) * K + sa * 8;
    const __hip_bfloat16* pAl0 = Al + (size_t)(bm * 128 + lr0) * K + sa * 8;
    const __hip_bfloat16* pAl1 = Al + (size_t)(bm * 128 + lr1) * K + sa * 8;
    const __hip_bfloat16* pWh0 = Wh + (size_t)(bn * 64 + lrW) * K + sw * 8;
    const __hip_bfloat16* pWl0 = Wl + (size_t)(bn * 64 + lrW) * K + sw * 8;

    short* dAh0 = smem + lr0 * 32 + ts * 8;
    short* dAh1 = smem + lr1 * 32 + ts * 8;
    short* dAl0 = smem + 12288 + lr0 * 32 + ts * 8;
    short* dAl1 = smem + 12288 + lr1 * 32 + ts * 8;
    short* dWh  = smem + 24576 + lrW * 32 + ts * 8;
    short* dWl  = smem + 30720 + lrW * 32 + ts * 8;

    const int rA = wm * 64 + (lane & 15);
    const int rB = wn * 32 + (lane & 15);
    const int pos = (lane >> 4) ^ ((lane >> 1) & 3);
    const short* baseA = smem + rA * 32 + pos * 8;            // Ah; Al at +12288
    const short* baseB = smem + 24576 + rB * 32 + pos * 8;    // Wh; Wl at +6144

    f32x4 acc[4][2] = {};

    auto STAGE = [&](int oA) {   // 6 gloads; oW = oA>>1
        int oW = oA >> 1;
        gload_lds16(pAh0, dAh0 + oA); gload_lds16(pAh1, dAh1 + oA);
        gload_lds16(pAl0, dAl0 + oA); gload_lds16(pAl1, dAl1 + oA);
        gload_lds16(pWh0, dWh + oW);  gload_lds16(pWl0, dWl + oW);
        pAh0 += 32; pAh1 += 32; pAl0 += 32; pAl1 += 32; pWh0 += 32; pWl0 += 32;
    };
    auto STEP = [&](int oA) {
        int oW = oA >> 1;
        bf16x8 ah[4], al[4], bh[2], bl[2];
#pragma unroll
        for (int m = 0; m < 4; ++m) {
            ah[m] = ldfrag(baseA + oA + m * 512);
            al[m] = ldfrag(baseA + 12288 + oA + m * 512);
        }
#pragma unroll
        for (int n = 0; n < 2; ++n) {
            bh[n] = ldfrag(baseB + oW + n * 512);
            bl[n] = ldfrag(baseB + 6144 + oW + n * 512);
        }
#pragma unroll
        for (int m = 0; m < 4; ++m)
#pragma unroll
            for (int n = 0; n < 2; ++n) {
                acc[m][n] = MFMA16(ah[m], bh[n], acc[m][n]);
                acc[m][n] = MFMA16(ah[m], bl[n], acc[m][n]);
                acc[m][n] = MFMA16(al[m], bh[n], acc[m][n]);
            }
    };

    STAGE(0); STAGE(4096);
    int oc = 0;
#pragma unroll 1
    for (int k = 0; k < nk - 1; ++k) {
        WAITV(6);
        BARRIER();
        int o2 = (oc == 0) ? 8192 : oc - 4096;
        if (k + 2 < nk) STAGE(o2);
        STEP(oc);
        oc = (oc == 8192) ? 0 : oc + 4096;
    }
    WAITV(0); BARRIER();
    STEP(oc);

    float bcol[2];
#pragma unroll
    for (int n = 0; n < 2; ++n) bcol[n] = bias[bn * 64 + wn * 32 + n * 16 + (lane & 15)];

#pragma unroll
    for (int m = 0; m < 4; ++m)
#pragma unroll
        for (int n = 0; n < 2; ++n)
#pragma unroll
            for (int j = 0; j < 4; ++j) {
                float v = acc[m][n][j] + bcol[n];
                acc[m][n][j] = v >= 0.f ? v : SLOPE * v;
            }
#pragma unroll
    for (int m = 0; m < 4; ++m)
#pragma unroll
        for (int n = 0; n < 2; ++n)
#pragma unroll
            for (int j = 0; j < 4; ++j) {
                int grow = bm * 128 + wm * 64 + m * 16 + (lane >> 4) * 4 + j;
                int gcol = bn * 64 + wn * 32 + n * 16 + (lane & 15);
                size_t idx = (size_t)grow * N + gcol;
                float v = acc[m][n][j];
                if (Cf) Cf[idx] = v;
                if (Ch) {
                    __hip_bfloat16 h = __float2bfloat16(v);
                    Ch[idx] = h;
                    Cl[idx] = __float2bfloat16(v - __bfloat162float(h));
                }
            }
    if (sumsq) {
#pragma unroll
        for (int m = 0; m < 4; ++m)
#pragma unroll
            for (int j = 0; j < 4; ++j) {
                float p = acc[m][0][j] * acc[m][0][j] + acc[m][1][j] * acc[m][1][j];
#pragma unroll
                for (int w = 1; w < 16; w <<= 1) p += __shfl_xor(p, w);
                if ((lane & 15) == 0) {
                    int grow = bm * 128 + wm * 64 + m * 16 + (lane >> 4) * 4 + j;
                    atomicAdd(&sumsq[grow], p);
                }
            }
    }
}

// ---- fused pairwise-distance statistics: TRIANGLE grid, all-resident ----
// 528 blocks (= 8 XCD chunks of 66, bijective). m97 geometry: 4 waves,
// 64x64/wave, 16 MFMA : 8 ds_read per step. Latent phase first (acc2[4][4]),
// converted to bf16-packed d2 (32 VGPR) at the transition; X phase (32 steps).
// 3 LDS buffer sets depth-2-ahead, WAITV(4) steady. Stats weight 2 off-diag.
// __launch_bounds__(256,3): cap VGPR so 3 blocks/CU -> all 528 resident.
__global__ __launch_bounds__(256, 3) void pairwise_corr(
    const __hip_bfloat16* __restrict__ Xh, const __hip_bfloat16* __restrict__ Lh,
    const float* __restrict__ r1, const float* __restrict__ r2,
    double* __restrict__ stats)
{
    // XCD-chunked bijective swizzle over the 528-block triangle (528 = 8*66)
    int swz = (blockIdx.x & 7) * 66 + (blockIdx.x >> 3);
    int rem = swz, bm = 0;
    while (rem >= 32 - bm) { rem -= 32 - bm; ++bm; }
    const int bn = bm + rem;                       // bm <= bn

    __shared__ short smem[24576];   // A@{0,4096,8192}, B@12288+{0,4096,8192}
    const int tid = threadIdx.x, lane = tid & 63, wave = tid >> 6;
    const int wm = wave >> 1, wn = wave & 1;

    const int lr0 = wave * 32 + (lane >> 2), lr1 = lr0 + 16;
    const int ts = lane & 3;
    const int sa = ts ^ ((lr0 >> 1) & 3);

    const __hip_bfloat16* pXa0 = Xh + (size_t)(bm * 128 + lr0) * D0 + sa * 8;
    const __hip_bfloat16* pXa1 = Xh + (size_t)(bm * 128 + lr1) * D0 + sa * 8;
    const __hip_bfloat16* pXb0 = Xh + (size_t)(bn * 128 + lr0) * D0 + sa * 8;
    const __hip_bfloat16* pXb1 = Xh + (size_t)(bn * 128 + lr1) * D0 + sa * 8;
    const __hip_bfloat16* qLa0 = Lh + (size_t)(bm * 128 + lr0) * DLAT + sa * 8;
    const __hip_bfloat16* qLa1 = Lh + (size_t)(bm * 128 + lr1) * DLAT + sa * 8;
    const __hip_bfloat16* qLb0 = Lh + (size_t)(bn * 128 + lr0) * DLAT + sa * 8;
    const __hip_bfloat16* qLb1 = Lh + (size_t)(bn * 128 + lr1) * DLAT + sa * 8;

    short* dA0 = smem + lr0 * 32 + ts * 8;
    short* dA1 = smem + lr1 * 32 + ts * 8;
    short* dB0 = smem + 12288 + lr0 * 32 + ts * 8;
    short* dB1 = smem + 12288 + lr1 * 32 + ts * 8;

    const int pos = (lane >> 4) ^ ((lane >> 1) & 3);
    const short* baseA = smem + (wm * 64 + (lane & 15)) * 32 + pos * 8;
    const short* baseB = smem + 12288 + (wn * 64 + (lane & 15)) * 32 + pos * 8;

    auto STAGEX = [&](int o) {   // 4 gloads per wave
        gload_lds16(pXa0, dA0 + o); gload_lds16(pXa1, dA1 + o);
        gload_lds16(pXb0, dB0 + o); gload_lds16(pXb1, dB1 + o);
        pXa0 += 32; pXa1 += 32; pXb0 += 32; pXb1 += 32;
    };
    auto STAGEL = [&](int o) {
        gload_lds16(qLa0, dA0 + o); gload_lds16(qLa1, dA1 + o);
        gload_lds16(qLb0, dB0 + o); gload_lds16(qLb1, dB1 + o);
        qLa0 += 32; qLa1 += 32; qLb0 += 32; qLb1 += 32;
    };

    f32x4 acc2[4][4] = {};
    auto STEP = [&](int o, f32x4 (&A)[4][4]) {
        bf16x8 a[4], b[4];
#pragma unroll
        for (int m = 0; m < 4; ++m) a[m] = ldfrag(baseA + o + m * 512);
#pragma unroll
        for (int n = 0; n < 4; ++n) b[n] = ldfrag(baseB + o + n * 512);
#pragma unroll
        for (int m = 0; m < 4; ++m)
#pragma unroll
            for (int n = 0; n < 4; ++n)
                A[m][n] = MFMA16(a[m], b[n], A[m][n]);
    };

    // prologue: r2 row norms (needed at phase transition; L2-hot, lands early)
    float r2i[4][4], r2j[4];
#pragma unroll
    for (int m = 0; m < 4; ++m)
#pragma unroll
        for (int j = 0; j < 4; ++j)
            r2i[m][j] = r2[bm * 128 + wm * 64 + m * 16 + (lane >> 4) * 4 + j];
#pragma unroll
    for (int n = 0; n < 4; ++n)
        r2j[n] = r2[bn * 128 + wn * 64 + n * 16 + (lane & 15)];

    STAGEL(0); STAGEL(4096);
    WAITV(4); BARRIER(); STAGEL(8192); STEP(0, acc2);      // c=L0, stage L2
    WAITV(4); BARRIER(); STAGEL(0);    STEP(4096, acc2);   // c=L1, stage L3
    WAITV(4); BARRIER(); STAGEX(4096); STEP(8192, acc2);   // c=L2, stage X0->buf1
    WAITV(4); BARRIER(); STAGEX(8192); STEP(0, acc2);      // c=L3, stage X1->buf2

    // --- phase transition: latent Gram -> distances; fold s2/s22; pack d2 ---
    float s2 = 0.f, s22 = 0.f;
    unsigned d2p[4][4][2];
#pragma unroll
    for (int m = 0; m < 4; ++m)
#pragma unroll
        for (int n = 0; n < 4; ++n)
#pragma unroll
            for (int jj = 0; jj < 2; ++jj) {
                float dv[2];
#pragma unroll
                for (int h = 0; h < 2; ++h) {
                    int j = jj * 2 + h;
                    int gi = bm * 128 + wm * 64 + m * 16 + (lane >> 4) * 4 + j;
                    int gj = bn * 128 + wn * 64 + n * 16 + (lane & 15);
                    float sq = r2i[m][j] + r2j[n] - 2.0f * acc2[m][n][j];
                    dv[h] = (gi == gj || sq <= 0.f) ? 0.f : sqrtf(sq);
                    s2 += dv[h]; s22 += dv[h] * dv[h];
                }
                d2p[m][n][jj] = packbf2(dv[0], dv[1]);
            }

    f32x4 acc[4][4];
#pragma unroll
    for (int m = 0; m < 4; ++m)
#pragma unroll
        for (int n = 0; n < 4; ++n)
#pragma unroll
            for (int j = 0; j < 4; ++j) acc[m][n][j] = 0.f;

    WAITV(4); BARRIER(); STAGEX(0);    STEP(4096, acc);    // c=X0, stage X2->buf0
    WAITV(4); BARRIER(); STAGEX(4096); STEP(8192, acc);    // c=X1, stage X3->buf1
#pragma unroll 1
    for (int k = 0; k < 9; ++k) {                          // c=X2..X28
        WAITV(4); BARRIER(); STAGEX(8192); STEP(0, acc);
        WAITV(4); BARRIER(); STAGEX(0);    STEP(4096, acc);
        WAITV(4); BARRIER(); STAGEX(4096); STEP(8192, acc);
    }
    WAITV(4); BARRIER(); STAGEX(8192); STEP(0, acc);       // c=X29, stage X31
    WAITV(4); BARRIER();               STEP(4096, acc);    // c=X30
    WAITV(0); BARRIER();               STEP(8192, acc);    // c=X31

    // --- final epilogue: d1 distances + 5 stats (weight 2 off-diagonal) ---
    float r1i[4][4], r1j[4];
#pragma unroll
    for (int m = 0; m < 4; ++m)
#pragma unroll
        for (int j = 0; j < 4; ++j)
            r1i[m][j] = r1[bm * 128 + wm * 64 + m * 16 + (lane >> 4) * 4 + j];
#pragma unroll
    for (int n = 0; n < 4; ++n)
        r1j[n] = r1[bn * 128 + wn * 64 + n * 16 + (lane & 15)];

    float s1 = 0.f, s11 = 0.f, s12 = 0.f;
#pragma unroll
    for (int m = 0; m < 4; ++m)
#pragma unroll
        for (int n = 0; n < 4; ++n)
#pragma unroll
            for (int j = 0; j < 4; ++j) {
                int gi = bm * 128 + wm * 64 + m * 16 + (lane >> 4) * 4 + j;
                int gj = bn * 128 + wn * 64 + n * 16 + (lane & 15);
                float sq1 = r1i[m][j] + r1j[n] - 2.0f * acc[m][n][j];
                float d1v = (gi == gj || sq1 <= 0.f) ? 0.f : sqrtf(sq1);
                float d2v = unpackbf(d2p[m][n][j >> 1], j & 1);
                s1 += d1v; s11 += d1v * d1v; s12 += d1v * d2v;
            }

    float vals[5] = { s1, s2, s11, s22, s12 };
#pragma unroll
    for (int q = 0; q < 5; ++q)
        for (int off = 32; off; off >>= 1) vals[q] += __shfl_down(vals[q], off);

    __syncthreads();                 // done with LDS; reuse as reduce buffer
    float* red = (float*)smem;
    if (lane == 0) {
#pragma unroll
        for (int q = 0; q < 5; ++q) red[wave * 5 + q] = vals[q];
    }
    __syncthreads();
    if (tid == 0) {
        double w = (bm == bn) ? 1.0 : 2.0;
#pragma unroll
        for (int q = 0; q < 5; ++q) {
            double tt = (double)red[q] + (double)red[5 + q] + (double)red[10 + q] + (double)red[15 + q];
            atomicAdd(&stats[q], w * tt);
        }
    }
}

// ---- fused hi/lo split for x + all 6 weights; also r1 = rowsumsq(x) ----
struct SplitSeg { const float* src; __hip_bfloat16* hi; __hip_bfloat16* lo; };
struct SplitArgs { SplitSeg s[7]; unsigned cum4[8]; };

__global__ void split_many(SplitArgs A, int total4, float* __restrict__ r1) {
    int v = blockIdx.x * blockDim.x + threadIdx.x;
    if (v >= total4) return;
    int si = 0;
#pragma unroll
    for (int i = 1; i < 7; ++i) si = (v >= (int)A.cum4[i]) ? i : si;
    int local = v - (int)A.cum4[si];
    float4 f = *(const float4*)(A.s[si].src + (size_t)local * 4);
    float fv[4] = { f.x, f.y, f.z, f.w };
    __hip_bfloat16* hi = A.s[si].hi;
    __hip_bfloat16* lo = A.s[si].lo;
#pragma unroll
    for (int j = 0; j < 4; ++j) {
        __hip_bfloat16 h = __float2bfloat16(fv[j]);
        hi[local * 4 + j] = h;
        lo[local * 4 + j] = __float2bfloat16(fv[j] - __bfloat162float(h));
    }
    if (blockIdx.x < 4096) {   // pure-x block == one row of x
        float s = fv[0]*fv[0] + fv[1]*fv[1] + fv[2]*fv[2] + fv[3]*fv[3];
        for (int off = 32; off; off >>= 1) s += __shfl_down(s, off);
        __shared__ float red[4];
        int lane = threadIdx.x & 63, wave = threadIdx.x >> 6;
        if (lane == 0) red[wave] = s;
        __syncthreads();
        if (threadIdx.x == 0) r1[blockIdx.x] = red[0] + red[1] + red[2] + red[3];
    }
}

__global__ void finalize_corr(const double* __restrict__ stats, float* __restrict__ corr_out) {
    double n = (double)NROW * (double)NROW;
    double s1 = stats[0], s2 = stats[1], s11 = stats[2], s22 = stats[3], s12 = stats[4];
    double m1 = s1 / n, m2 = s2 / n;
    double cov = s12 / n - m1 * m2;                  // biased (mean)
    double v1 = (s11 - n * m1 * m1) / (n - 1.0);     // unbiased (ddof=1)
    double v2 = (s22 - n * m2 * m2) / (n - 1.0);
    corr_out[0] = (float)(cov / sqrt(v1 * v2));
}

extern "C" void kernel_launch(void* const* d_in, const int* in_sizes, int n_in,
                              void* d_out, int out_size, void* d_ws, size_t ws_size,
                              hipStream_t stream) {
    const float* x   = (const float*)d_in[0];
    const float* We1 = (const float*)d_in[1];  const float* be1 = (const float*)d_in[2];
    const float* We2 = (const float*)d_in[3];  const float* be2 = (const float*)d_in[4];
    const float* We3 = (const float*)d_in[5];  const float* be3 = (const float*)d_in[6];
    const float* Wd1 = (const float*)d_in[7];  const float* bd1 = (const float*)d_in[8];
    const float* Wd2 = (const float*)d_in[9];  const float* bd2 = (const float*)d_in[10];
    const float* Wd3 = (const float*)d_in[11]; const float* bd3 = (const float*)d_in[12];
    float* out = (float*)d_out;

    char* ws = (char*)d_ws;
    size_t off = 0;
    auto alloc = [&](size_t bytes) -> char* {
        char* p = ws + off; off += (bytes + 255) & ~(size_t)255; return p;
    };
    typedef __hip_bfloat16 bf;
    bf* xh  = (bf*)alloc((size_t)NROW * D0 * 2);   bf* xl  = (bf*)alloc((size_t)NROW * D0 * 2);
    bf* w1h = (bf*)alloc((size_t)DH1 * D0 * 2);    bf* w1l = (bf*)alloc((size_t)DH1 * D0 * 2);
    bf* w2h = (bf*)alloc((size_t)DH2 * DH1 * 2);   bf* w2l = (bf*)alloc((size_t)DH2 * DH1 * 2);
    bf* w3h = (bf*)alloc((size_t)DLAT * DH2 * 2);  bf* w3l = (bf*)alloc((size_t)DLAT * DH2 * 2);
    bf* w4h = (bf*)alloc((size_t)DH2 * DLAT * 2);  bf* w4l = (bf*)alloc((size_t)DH2 * DLAT * 2);
    bf* w5h = (bf*)alloc((size_t)DH1 * DH2 * 2);   bf* w5l = (bf*)alloc((size_t)DH1 * DH2 * 2);
    bf* w6h = (bf*)alloc((size_t)D0 * DH1 * 2);    bf* w6l = (bf*)alloc((size_t)D0 * DH1 * 2);
    bf* h1h = (bf*)alloc((size_t)NROW * DH1 * 2);  bf* h1l = (bf*)alloc((size_t)NROW * DH1 * 2);
    bf* h2h = (bf*)alloc((size_t)NROW * DH2 * 2);  bf* h2l = (bf*)alloc((size_t)NROW * DH2 * 2);
    bf* lth = (bf*)alloc((size_t)NROW * DLAT * 2); bf* ltl = (bf*)alloc((size_t)NROW * DLAT * 2);
    bf* d4h = (bf*)alloc((size_t)NROW * DH2 * 2);  bf* d4l = (bf*)alloc((size_t)NROW * DH2 * 2);
    bf* d5h = (bf*)alloc((size_t)NROW * DH1 * 2);  bf* d5l = (bf*)alloc((size_t)NROW * DH1 * 2);
    float* r1v = (float*)alloc((size_t)NROW * 4);
    float* r2v = (float*)alloc((size_t)NROW * 4);      // 16384 B, 256-aligned
    double* stats = (double*)alloc(5 * 8);             // contiguous after r2v

    // zero r2v + stats in one async memset (graph-capture safe)
    hipMemsetAsync(r2v, 0, (size_t)NROW * 4 + 256, stream);

    SplitArgs SA;
    const float* srcs[7] = { x, We1, We2, We3, Wd1, Wd2, Wd3 };
    bf* his[7] = { xh, w1h, w2h, w3h, w4h, w5h, w6h };
    bf* los[7] = { xl, w1l, w2l, w3l, w4l, w5l, w6l };
    unsigned ns[7] = { NROW * D0, DH1 * D0, DH2 * DH1, DLAT * DH2,
                       DH2 * DLAT, DH1 * DH2, D0 * DH1 };
    unsigned cum = 0;
    for (int i = 0; i < 7; ++i) {
        SA.s[i].src = srcs[i]; SA.s[i].hi = his[i]; SA.s[i].lo = los[i];
        SA.cum4[i] = cum; cum += ns[i] / 4;
    }
    SA.cum4[7] = cum;
    split_many<<<(cum + 255) / 256, 256, 0, stream>>>(SA, (int)cum, r1v);

    // encoder
    gemm_lrelu<<<dim3(NROW / 128, DH1 / 64), 256, 0, stream>>>(
        xh, xl, w1h, w1l, be1, nullptr, h1h, h1l, nullptr, DH1, D0);
    gemm_lrelu<<<dim3(NROW / 128, DH2 / 64), 256, 0, stream>>>(
        h1h, h1l, w2h, w2l, be2, nullptr, h2h, h2l, nullptr, DH2, DH1);
    gemm_lrelu<<<dim3(NROW / 128, DLAT / 64), 256, 0, stream>>>(
        h2h, h2l, w3h, w3l, be3, nullptr, lth, ltl, r2v, DLAT, DH2);
    // decoder
    gemm_lrelu<<<dim3(NROW / 128, DH2 / 64), 256, 0, stream>>>(
        lth, ltl, w4h, w4l, bd1, nullptr, d4h, d4l, nullptr, DH2, DLAT);
    gemm_lrelu<<<dim3(NROW / 128, DH1 / 64), 256, 0, stream>>>(
        d4h, d4l, w5h, w5l, bd2, nullptr, d5h, d5l, nullptr, DH1, DH2);
    gemm_lrelu<<<dim3(NROW / 128, D0 / 64), 256, 0, stream>>>(
        d5h, d5l, w6h, w6l, bd3, out, nullptr, nullptr, nullptr, D0, DH1);

    // fused pairwise-distance correlation statistics (triangle: 528 blocks)
    pairwise_corr<<<dim3(528), 256, 0, stream>>>(xh, lth, r1v, r2v, stats);
    finalize_corr<<<1, 1, 0, stream>>>(stats, out + (size_t)NROW * D0);
}

// Round 9
// 249.616 us; speedup vs baseline: 1.1719x; 1.0196x over previous
//
#include <hip/hip_runtime.h>
#include <hip/hip_bf16.h>

#define NROW 4096
#define D0   1024
#define DH1  512
#define DH2  256
#define DLAT 128
#define SLOPE 0.01f

typedef float f32x4 __attribute__((ext_vector_type(4)));
typedef __bf16 bf16x8 __attribute__((ext_vector_type(8)));
typedef short short8 __attribute__((ext_vector_type(8)));

#define WAITV(N) asm volatile("s_waitcnt vmcnt(" #N ")" ::: "memory")
#define BARRIER() do { __builtin_amdgcn_s_barrier(); __builtin_amdgcn_sched_barrier(0); } while (0)

// ---- async global->LDS 16B (wave-uniform base + lane*16 dest) ----
__device__ __forceinline__ void gload_lds16(const void* gp, void* lp) {
    __builtin_amdgcn_global_load_lds(
        (const __attribute__((address_space(1))) void*)(unsigned long long)gp,
        (__attribute__((address_space(3))) void*)(unsigned int)(unsigned long long)lp,
        16, 0, 0);
}

__device__ __forceinline__ bf16x8 ldfrag(const short* p) {
    union { short8 s; bf16x8 b; } u;
    u.s = *reinterpret_cast<const short8*>(p);
    return u.b;
}

__device__ __forceinline__ unsigned packbf2(float a, float b) {
    union { __hip_bfloat16 h; unsigned short u; } ua, ub;
    ua.h = __float2bfloat16(a); ub.h = __float2bfloat16(b);
    return (unsigned)ua.u | ((unsigned)ub.u << 16);
}
__device__ __forceinline__ float unpackbf(unsigned p, int hi) {
    union { unsigned short u; __hip_bfloat16 h; } t;
    t.u = (unsigned short)(hi ? (p >> 16) : p);
    return __bfloat162float(t.h);
}

#define MFMA16(A, B, C) __builtin_amdgcn_mfma_f32_16x16x32_bf16((A), (B), (C), 0, 0, 0)

// ---- split-precision GEMM: C = lrelu(A @ W^T + b), BM=128 BN=64 ----
// Depth-3 counted-vmcnt pipeline (3 LDS buffer sets, WAITV(6) steady state).
// 3-MFMA split: ah*bh + ah*bl + al*bh (residual ~2^-18 relative).
__global__ __launch_bounds__(256, 2) void gemm_lrelu(
    const __hip_bfloat16* __restrict__ Ah, const __hip_bfloat16* __restrict__ Al,
    const __hip_bfloat16* __restrict__ Wh, const __hip_bfloat16* __restrict__ Wl,
    const float* __restrict__ bias,
    float* __restrict__ Cf, __hip_bfloat16* __restrict__ Ch, __hip_bfloat16* __restrict__ Cl,
    float* __restrict__ sumsq, int N, int K)
{
    __shared__ short smem[36864];
    const int tid = threadIdx.x, lane = tid & 63, wave = tid >> 6;
    const int wm = wave >> 1, wn = wave & 1;
    const int bm = blockIdx.x, bn = blockIdx.y;
    const int nk = K >> 5;

    const int lr0 = wave * 32 + (lane >> 2), lr1 = lr0 + 16;
    const int lrW = wave * 16 + (lane >> 2);
    const int ts  = lane & 3;
    const int sa  = ts ^ ((lr0 >> 1) & 3);
    const int sw  = ts ^ ((lrW >> 1) & 3);

    const __hip_bfloat16* pAh0 = Ah + (size_t)(bm * 128 + lr0) * K + sa * 8;
    const __hip_bfloat16* pAh1 = Ah + (size_t)(bm * 128 + lr1) * K + sa * 8;
    const __hip_bfloat16* pAl0 = Al + (size_t)(bm * 128 + lr0) * K + sa * 8;
    const __hip_bfloat16* pAl1 = Al + (size_t)(bm * 128 + lr1) * K + sa * 8;
    const __hip_bfloat16* pWh0 = Wh + (size_t)(bn * 64 + lrW) * K + sw * 8;
    const __hip_bfloat16* pWl0 = Wl + (size_t)(bn * 64 + lrW) * K + sw * 8;

    short* dAh0 = smem + lr0 * 32 + ts * 8;
    short* dAh1 = smem + lr1 * 32 + ts * 8;
    short* dAl0 = smem + 12288 + lr0 * 32 + ts * 8;
    short* dAl1 = smem + 12288 + lr1 * 32 + ts * 8;
    short* dWh  = smem + 24576 + lrW * 32 + ts * 8;
    short* dWl  = smem + 30720 + lrW * 32 + ts * 8;

    const int rA = wm * 64 + (lane & 15);
    const int rB = wn * 32 + (lane & 15);
    const int pos = (lane >> 4) ^ ((lane >> 1) & 3);
    const short* baseA = smem + rA * 32 + pos * 8;            // Ah; Al at +12288
    const short* baseB = smem + 24576 + rB * 32 + pos * 8;    // Wh; Wl at +6144

    f32x4 acc[4][2] = {};

    auto STAGE = [&](int oA) {   // 6 gloads; oW = oA>>1
        int oW = oA >> 1;
        gload_lds16(pAh0, dAh0 + oA); gload_lds16(pAh1, dAh1 + oA);
        gload_lds16(pAl0, dAl0 + oA); gload_lds16(pAl1, dAl1 + oA);
        gload_lds16(pWh0, dWh + oW);  gload_lds16(pWl0, dWl + oW);
        pAh0 += 32; pAh1 += 32; pAl0 += 32; pAl1 += 32; pWh0 += 32; pWl0 += 32;
    };
    auto STEP = [&](int oA) {
        int oW = oA >> 1;
        bf16x8 ah[4], al[4], bh[2], bl[2];
#pragma unroll
        for (int m = 0; m < 4; ++m) {
            ah[m] = ldfrag(baseA + oA + m * 512);
            al[m] = ldfrag(baseA + 12288 + oA + m * 512);
        }
#pragma unroll
        for (int n = 0; n < 2; ++n) {
            bh[n] = ldfrag(baseB + oW + n * 512);
            bl[n] = ldfrag(baseB + 6144 + oW + n * 512);
        }
#pragma unroll
        for (int m = 0; m < 4; ++m)
#pragma unroll
            for (int n = 0; n < 2; ++n) {
                acc[m][n] = MFMA16(ah[m], bh[n], acc[m][n]);
                acc[m][n] = MFMA16(ah[m], bl[n], acc[m][n]);
                acc[m][n] = MFMA16(al[m], bh[n], acc[m][n]);
            }
    };

    STAGE(0); STAGE(4096);
    int oc = 0;
#pragma unroll 1
    for (int k = 0; k < nk - 1; ++k) {
        WAITV(6);
        BARRIER();
        int o2 = (oc == 0) ? 8192 : oc - 4096;
        if (k + 2 < nk) STAGE(o2);
        STEP(oc);
        oc = (oc == 8192) ? 0 : oc + 4096;
    }
    WAITV(0); BARRIER();
    STEP(oc);

    float bcol[2];
#pragma unroll
    for (int n = 0; n < 2; ++n) bcol[n] = bias[bn * 64 + wn * 32 + n * 16 + (lane & 15)];

#pragma unroll
    for (int m = 0; m < 4; ++m)
#pragma unroll
        for (int n = 0; n < 2; ++n)
#pragma unroll
            for (int j = 0; j < 4; ++j) {
                float v = acc[m][n][j] + bcol[n];
                acc[m][n][j] = v >= 0.f ? v : SLOPE * v;
            }
#pragma unroll
    for (int m = 0; m < 4; ++m)
#pragma unroll
        for (int n = 0; n < 2; ++n)
#pragma unroll
            for (int j = 0; j < 4; ++j) {
                int grow = bm * 128 + wm * 64 + m * 16 + (lane >> 4) * 4 + j;
                int gcol = bn * 64 + wn * 32 + n * 16 + (lane & 15);
                size_t idx = (size_t)grow * N + gcol;
                float v = acc[m][n][j];
                if (Cf) Cf[idx] = v;
                if (Ch) {
                    __hip_bfloat16 h = __float2bfloat16(v);
                    Ch[idx] = h;
                    Cl[idx] = __float2bfloat16(v - __bfloat162float(h));
                }
            }
    if (sumsq) {
#pragma unroll
        for (int m = 0; m < 4; ++m)
#pragma unroll
            for (int j = 0; j < 4; ++j) {
                float p = acc[m][0][j] * acc[m][0][j] + acc[m][1][j] * acc[m][1][j];
#pragma unroll
                for (int w = 1; w < 16; w <<= 1) p += __shfl_xor(p, w);
                if ((lane & 15) == 0) {
                    int grow = bm * 128 + wm * 64 + m * 16 + (lane >> 4) * 4 + j;
                    atomicAdd(&sumsq[grow], p);
                }
            }
    }
}

// ---- fused pairwise-distance statistics: TRIANGLE grid, X-phase FIRST ----
// 528 blocks (8 XCD chunks of 66). m97 geometry: 4 waves, 64x64/wave.
// X Gram (32 steps, acc[4][4]) -> convert to d1, fold s1/s11, pack d1 to bf16
// pairs (32 VGPR, acc freed) -> latent Gram (4 steps, acc2[4][4]) -> epilogue.
// Peak live regs ~130-150 < (256,3) cap ~170 -> no spill, 3 blocks/CU.
// Step g consumes buf g%3, stages buf (g+2)%3; WAITV(4) steady, tail 4->0.
__global__ __launch_bounds__(256, 3) void pairwise_corr(
    const __hip_bfloat16* __restrict__ Xh, const __hip_bfloat16* __restrict__ Lh,
    const float* __restrict__ r1, const float* __restrict__ r2,
    double* __restrict__ stats)
{
    // XCD-chunked bijective swizzle over the 528-block triangle (528 = 8*66)
    int swz = (blockIdx.x & 7) * 66 + (blockIdx.x >> 3);
    int rem = swz, bm = 0;
    while (rem >= 32 - bm) { rem -= 32 - bm; ++bm; }
    const int bn = bm + rem;                       // bm <= bn

    __shared__ short smem[24576];   // A@{0,4096,8192}, B@12288+{0,4096,8192}
    const int tid = threadIdx.x, lane = tid & 63, wave = tid >> 6;
    const int wm = wave >> 1, wn = wave & 1;

    const int lr0 = wave * 32 + (lane >> 2), lr1 = lr0 + 16;
    const int ts = lane & 3;
    const int sa = ts ^ ((lr0 >> 1) & 3);

    const __hip_bfloat16* pXa0 = Xh + (size_t)(bm * 128 + lr0) * D0 + sa * 8;
    const __hip_bfloat16* pXa1 = Xh + (size_t)(bm * 128 + lr1) * D0 + sa * 8;
    const __hip_bfloat16* pXb0 = Xh + (size_t)(bn * 128 + lr0) * D0 + sa * 8;
    const __hip_bfloat16* pXb1 = Xh + (size_t)(bn * 128 + lr1) * D0 + sa * 8;

    short* dA0 = smem + lr0 * 32 + ts * 8;
    short* dA1 = smem + lr1 * 32 + ts * 8;
    short* dB0 = smem + 12288 + lr0 * 32 + ts * 8;
    short* dB1 = smem + 12288 + lr1 * 32 + ts * 8;

    const int pos = (lane >> 4) ^ ((lane >> 1) & 3);
    const short* baseA = smem + (wm * 64 + (lane & 15)) * 32 + pos * 8;
    const short* baseB = smem + 12288 + (wn * 64 + (lane & 15)) * 32 + pos * 8;

    auto STAGEX = [&](int o) {   // 4 gloads per wave
        gload_lds16(pXa0, dA0 + o); gload_lds16(pXa1, dA1 + o);
        gload_lds16(pXb0, dB0 + o); gload_lds16(pXb1, dB1 + o);
        pXa0 += 32; pXa1 += 32; pXb0 += 32; pXb1 += 32;
    };

    f32x4 acc[4][4] = {};
    auto STEP = [&](int o, f32x4 (&A)[4][4]) {
        bf16x8 a[4], b[4];
#pragma unroll
        for (int m = 0; m < 4; ++m) a[m] = ldfrag(baseA + o + m * 512);
#pragma unroll
        for (int n = 0; n < 4; ++n) b[n] = ldfrag(baseB + o + n * 512);
#pragma unroll
        for (int m = 0; m < 4; ++m)
#pragma unroll
            for (int n = 0; n < 4; ++n)
                A[m][n] = MFMA16(a[m], b[n], A[m][n]);
    };

    // prologue: r1 row norms (needed at the X->L transition)
    float r1i[4][4], r1j[4];
#pragma unroll
    for (int m = 0; m < 4; ++m)
#pragma unroll
        for (int j = 0; j < 4; ++j)
            r1i[m][j] = r1[bm * 128 + wm * 64 + m * 16 + (lane >> 4) * 4 + j];
#pragma unroll
    for (int n = 0; n < 4; ++n)
        r1j[n] = r1[bn * 128 + wn * 64 + n * 16 + (lane & 15)];

    STAGEX(0); STAGEX(4096);                               // stages X0, X1
    WAITV(4); BARRIER(); STAGEX(8192); STEP(0, acc);       // g=X0, stage X2
    WAITV(4); BARRIER(); STAGEX(0);    STEP(4096, acc);    // g=X1, stage X3
#pragma unroll 1
    for (int k = 0; k < 9; ++k) {                          // g=X2..X28
        WAITV(4); BARRIER(); STAGEX(4096); STEP(8192, acc);
        WAITV(4); BARRIER(); STAGEX(8192); STEP(0, acc);
        WAITV(4); BARRIER(); STAGEX(0);    STEP(4096, acc);
    }
    WAITV(4); BARRIER(); STAGEX(4096); STEP(8192, acc);    // g=X29, stage X31

    // switch staging source to latent (L tile: 4 stages of 32 cols)
    const __hip_bfloat16* qLa0 = Lh + (size_t)(bm * 128 + lr0) * DLAT + sa * 8;
    const __hip_bfloat16* qLa1 = Lh + (size_t)(bm * 128 + lr1) * DLAT + sa * 8;
    const __hip_bfloat16* qLb0 = Lh + (size_t)(bn * 128 + lr0) * DLAT + sa * 8;
    const __hip_bfloat16* qLb1 = Lh + (size_t)(bn * 128 + lr1) * DLAT + sa * 8;
    auto STAGEL = [&](int o) {
        gload_lds16(qLa0, dA0 + o); gload_lds16(qLa1, dA1 + o);
        gload_lds16(qLb0, dB0 + o); gload_lds16(qLb1, dB1 + o);
        qLa0 += 32; qLa1 += 32; qLb0 += 32; qLb1 += 32;
    };

    WAITV(4); BARRIER(); STAGEL(8192); STEP(0, acc);       // g=X30, stage L0->buf2
    WAITV(4); BARRIER(); STAGEL(0);    STEP(4096, acc);    // g=X31, stage L1->buf0

    // --- transition: X Gram complete -> d1 distances; fold s1/s11; pack d1 ---
    float s1 = 0.f, s11 = 0.f;
    unsigned d1p[4][4][2];
#pragma unroll
    for (int m = 0; m < 4; ++m)
#pragma unroll
        for (int n = 0; n < 4; ++n)
#pragma unroll
            for (int jj = 0; jj < 2; ++jj) {
                float dv[2];
#pragma unroll
                for (int h = 0; h < 2; ++h) {
                    int j = jj * 2 + h;
                    int gi = bm * 128 + wm * 64 + m * 16 + (lane >> 4) * 4 + j;
                    int gj = bn * 128 + wn * 64 + n * 16 + (lane & 15);
                    float sq = r1i[m][j] + r1j[n] - 2.0f * acc[m][n][j];
                    dv[h] = (gi == gj || sq <= 0.f) ? 0.f : sqrtf(sq);
                    s1 += dv[h]; s11 += dv[h] * dv[h];
                }
                d1p[m][n][jj] = packbf2(dv[0], dv[1]);
            }

    f32x4 acc2[4][4];
#pragma unroll
    for (int m = 0; m < 4; ++m)
#pragma unroll
        for (int n = 0; n < 4; ++n)
#pragma unroll
            for (int j = 0; j < 4; ++j) acc2[m][n][j] = 0.f;

    WAITV(4); BARRIER(); STAGEL(4096); STEP(8192, acc2);   // g=L0, stage L2->buf1
    WAITV(4); BARRIER(); STAGEL(8192); STEP(0, acc2);      // g=L1, stage L3->buf2
    WAITV(4); BARRIER();               STEP(4096, acc2);   // g=L2
    WAITV(0); BARRIER();               STEP(8192, acc2);   // g=L3

    // --- final epilogue: d2 distances + remaining stats (weight 2 off-diag) ---
    float r2i[4][4], r2j[4];
#pragma unroll
    for (int m = 0; m < 4; ++m)
#pragma unroll
        for (int j = 0; j < 4; ++j)
            r2i[m][j] = r2[bm * 128 + wm * 64 + m * 16 + (lane >> 4) * 4 + j];
#pragma unroll
    for (int n = 0; n < 4; ++n)
        r2j[n] = r2[bn * 128 + wn * 64 + n * 16 + (lane & 15)];

    float s2 = 0.f, s22 = 0.f, s12 = 0.f;
#pragma unroll
    for (int m = 0; m < 4; ++m)
#pragma unroll
        for (int n = 0; n < 4; ++n)
#pragma unroll
            for (int j = 0; j < 4; ++j) {
                int gi = bm * 128 + wm * 64 + m * 16 + (lane >> 4) * 4 + j;
                int gj = bn * 128 + wn * 64 + n * 16 + (lane & 15);
                float sq2 = r2i[m][j] + r2j[n] - 2.0f * acc2[m][n][j];
                float d2v = (gi == gj || sq2 <= 0.f) ? 0.f : sqrtf(sq2);
                float d1v = unpackbf(d1p[m][n][j >> 1], j & 1);
                s2 += d2v; s22 += d2v * d2v; s12 += d1v * d2v;
            }

    float vals[5] = { s1, s2, s11, s22, s12 };
#pragma unroll
    for (int q = 0; q < 5; ++q)
        for (int off = 32; off; off >>= 1) vals[q] += __shfl_down(vals[q], off);

    __syncthreads();                 // done with LDS; reuse as reduce buffer
    float* red = (float*)smem;
    if (lane == 0) {
#pragma unroll
        for (int q = 0; q < 5; ++q) red[wave * 5 + q] = vals[q];
    }
    __syncthreads();
    if (tid == 0) {
        double w = (bm == bn) ? 1.0 : 2.0;
#pragma unroll
        for (int q = 0; q < 5; ++q) {
            double tt = (double)red[q] + (double)red[5 + q] + (double)red[10 + q] + (double)red[15 + q];
            atomicAdd(&stats[q], w * tt);
        }
    }
}

// ---- fused hi/lo split for x + all 6 weights; also r1 = rowsumsq(x) ----
struct SplitSeg { const float* src; __hip_bfloat16* hi; __hip_bfloat16* lo; };
struct SplitArgs { SplitSeg s[7]; unsigned cum4[8]; };

__global__ void split_many(SplitArgs A, int total4, float* __restrict__ r1) {
    int v = blockIdx.x * blockDim.x + threadIdx.x;
    if (v >= total4) return;
    int si = 0;
#pragma unroll
    for (int i = 1; i < 7; ++i) si = (v >= (int)A.cum4[i]) ? i : si;
    int local = v - (int)A.cum4[si];
    float4 f = *(const float4*)(A.s[si].src + (size_t)local * 4);
    float fv[4] = { f.x, f.y, f.z, f.w };
    __hip_bfloat16* hi = A.s[si].hi;
    __hip_bfloat16* lo = A.s[si].lo;
#pragma unroll
    for (int j = 0; j < 4; ++j) {
        __hip_bfloat16 h = __float2bfloat16(fv[j]);
        hi[local * 4 + j] = h;
        lo[local * 4 + j] = __float2bfloat16(fv[j] - __bfloat162float(h));
    }
    if (blockIdx.x < 4096) {   // pure-x block == one row of x
        float s = fv[0]*fv[0] + fv[1]*fv[1] + fv[2]*fv[2] + fv[3]*fv[3];
        for (int off = 32; off; off >>= 1) s += __shfl_down(s, off);
        __shared__ float red[4];
        int lane = threadIdx.x & 63, wave = threadIdx.x >> 6;
        if (lane == 0) red[wave] = s;
        __syncthreads();
        if (threadIdx.x == 0) r1[blockIdx.x] = red[0] + red[1] + red[2] + red[3];
    }
}

__global__ void finalize_corr(const double* __restrict__ stats, float* __restrict__ corr_out) {
    double n = (double)NROW * (double)NROW;
    double s1 = stats[0], s2 = stats[1], s11 = stats[2], s22 = stats[3], s12 = stats[4];
    double m1 = s1 / n, m2 = s2 / n;
    double cov = s12 / n - m1 * m2;                  // biased (mean)
    double v1 = (s11 - n * m1 * m1) / (n - 1.0);     // unbiased (ddof=1)
    double v2 = (s22 - n * m2 * m2) / (n - 1.0);
    corr_out[0] = (float)(cov / sqrt(v1 * v2));
}

extern "C" void kernel_launch(void* const* d_in, const int* in_sizes, int n_in,
                              void* d_out, int out_size, void* d_ws, size_t ws_size,
                              hipStream_t stream) {
    const float* x   = (const float*)d_in[0];
    const float* We1 = (const float*)d_in[1];  const float* be1 = (const float*)d_in[2];
    const float* We2 = (const float*)d_in[3];  const float* be2 = (const float*)d_in[4];
    const float* We3 = (const float*)d_in[5];  const float* be3 = (const float*)d_in[6];
    const float* Wd1 = (const float*)d_in[7];  const float* bd1 = (const float*)d_in[8];
    const float* Wd2 = (const float*)d_in[9];  const float* bd2 = (const float*)d_in[10];
    const float* Wd3 = (const float*)d_in[11]; const float* bd3 = (const float*)d_in[12];
    float* out = (float*)d_out;

    char* ws = (char*)d_ws;
    size_t off = 0;
    auto alloc = [&](size_t bytes) -> char* {
        char* p = ws + off; off += (bytes + 255) & ~(size_t)255; return p;
    };
    typedef __hip_bfloat16 bf;
    bf* xh  = (bf*)alloc((size_t)NROW * D0 * 2);   bf* xl  = (bf*)alloc((size_t)NROW * D0 * 2);
    bf* w1h = (bf*)alloc((size_t)DH1 * D0 * 2);    bf* w1l = (bf*)alloc((size_t)DH1 * D0 * 2);
    bf* w2h = (bf*)alloc((size_t)DH2 * DH1 * 2);   bf* w2l = (bf*)alloc((size_t)DH2 * DH1 * 2);
    bf* w3h = (bf*)alloc((size_t)DLAT * DH2 * 2);  bf* w3l = (bf*)alloc((size_t)DLAT * DH2 * 2);
    bf* w4h = (bf*)alloc((size_t)DH2 * DLAT * 2);  bf* w4l = (bf*)alloc((size_t)DH2 * DLAT * 2);
    bf* w5h = (bf*)alloc((size_t)DH1 * DH2 * 2);   bf* w5l = (bf*)alloc((size_t)DH1 * DH2 * 2);
    bf* w6h = (bf*)alloc((size_t)D0 * DH1 * 2);    bf* w6l = (bf*)alloc((size_t)D0 * DH1 * 2);
    bf* h1h = (bf*)alloc((size_t)NROW * DH1 * 2);  bf* h1l = (bf*)alloc((size_t)NROW * DH1 * 2);
    bf* h2h = (bf*)alloc((size_t)NROW * DH2 * 2);  bf* h2l = (bf*)alloc((size_t)NROW * DH2 * 2);
    bf* lth = (bf*)alloc((size_t)NROW * DLAT * 2); bf* ltl = (bf*)alloc((size_t)NROW * DLAT * 2);
    bf* d4h = (bf*)alloc((size_t)NROW * DH2 * 2);  bf* d4l = (bf*)alloc((size_t)NROW * DH2 * 2);
    bf* d5h = (bf*)alloc((size_t)NROW * DH1 * 2);  bf* d5l = (bf*)alloc((size_t)NROW * DH1 * 2);
    float* r1v = (float*)alloc((size_t)NROW * 4);
    float* r2v = (float*)alloc((size_t)NROW * 4);      // 16384 B, 256-aligned
    double* stats = (double*)alloc(5 * 8);             // contiguous after r2v

    // zero r2v + stats in one async memset (graph-capture safe)
    hipMemsetAsync(r2v, 0, (size_t)NROW * 4 + 256, stream);

    SplitArgs SA;
    const float* srcs[7] = { x, We1, We2, We3, Wd1, Wd2, Wd3 };
    bf* his[7] = { xh, w1h, w2h, w3h, w4h, w5h, w6h };
    bf* los[7] = { xl, w1l, w2l, w3l, w4l, w5l, w6l };
    unsigned ns[7] = { NROW * D0, DH1 * D0, DH2 * DH1, DLAT * DH2,
                       DH2 * DLAT, DH1 * DH2, D0 * DH1 };
    unsigned cum = 0;
    for (int i = 0; i < 7; ++i) {
        SA.s[i].src = srcs[i]; SA.s[i].hi = his[i]; SA.s[i].lo = los[i];
        SA.cum4[i] = cum; cum += ns[i] / 4;
    }
    SA.cum4[7] = cum;
    split_many<<<(cum + 255) / 256, 256, 0, stream>>>(SA, (int)cum, r1v);

    // encoder
    gemm_lrelu<<<dim3(NROW / 128, DH1 / 64), 256, 0, stream>>>(
        xh, xl, w1h, w1l, be1, nullptr, h1h, h1l, nullptr, DH1, D0);
    gemm_lrelu<<<dim3(NROW / 128, DH2 / 64), 256, 0, stream>>>(
        h1h, h1l, w2h, w2l, be2, nullptr, h2h, h2l, nullptr, DH2, DH1);
    gemm_lrelu<<<dim3(NROW / 128, DLAT / 64), 256, 0, stream>>>(
        h2h, h2l, w3h, w3l, be3, nullptr, lth, ltl, r2v, DLAT, DH2);
    // decoder
    gemm_lrelu<<<dim3(NROW / 128, DH2 / 64), 256, 0, stream>>>(
        lth, ltl, w4h, w4l, bd1, nullptr, d4h, d4l, nullptr, DH2, DLAT);
    gemm_lrelu<<<dim3(NROW / 128, DH1 / 64), 256, 0, stream>>>(
        d4h, d4l, w5h, w5l, bd2, nullptr, d5h, d5l, nullptr, DH1, DH2);
    gemm_lrelu<<<dim3(NROW / 128, D0 / 64), 256, 0, stream>>>(
        d5h, d5l, w6h, w6l, bd3, out, nullptr, nullptr, nullptr, D0, DH1);

    // fused pairwise-distance correlation statistics (triangle: 528 blocks)
    pairwise_corr<<<dim3(528), 256, 0, stream>>>(xh, lth, r1v, r2v, stats);
    finalize_corr<<<1, 1, 0, stream>>>(stats, out + (size_t)NROW * D0);
}

// Round 10
// 244.581 us; speedup vs baseline: 1.1961x; 1.0206x over previous
//
#include <hip/hip_runtime.h>
#include <hip/hip_bf16.h>

#define NROW 4096
#define D0   1024
#define DH1  512
#define DH2  256
#define DLAT 128
#define SLOPE 0.01f

typedef float f32x4 __attribute__((ext_vector_type(4)));
typedef __bf16 bf16x8 __attribute__((ext_vector_type(8)));
typedef short short8 __attribute__((ext_vector_type(8)));

#define WAITV(N) asm volatile("s_waitcnt vmcnt(" #N ")" ::: "memory")
#define BARRIER() do { __builtin_amdgcn_s_barrier(); __builtin_amdgcn_sched_barrier(0); } while (0)

// ---- async global->LDS 16B (wave-uniform base + lane*16 dest) ----
__device__ __forceinline__ void gload_lds16(const void* gp, void* lp) {
    __builtin_amdgcn_global_load_lds(
        (const __attribute__((address_space(1))) void*)(unsigned long long)gp,
        (__attribute__((address_space(3))) void*)(unsigned int)(unsigned long long)lp,
        16, 0, 0);
}

__device__ __forceinline__ bf16x8 ldfrag(const short* p) {
    union { short8 s; bf16x8 b; } u;
    u.s = *reinterpret_cast<const short8*>(p);
    return u.b;
}

__device__ __forceinline__ unsigned packbf2(float a, float b) {
    union { __hip_bfloat16 h; unsigned short u; } ua, ub;
    ua.h = __float2bfloat16(a); ub.h = __float2bfloat16(b);
    return (unsigned)ua.u | ((unsigned)ub.u << 16);
}
__device__ __forceinline__ float unpackbf(unsigned p, int hi) {
    union { unsigned short u; __hip_bfloat16 h; } t;
    t.u = (unsigned short)(hi ? (p >> 16) : p);
    return __bfloat162float(t.h);
}

#define MFMA16(A, B, C) __builtin_amdgcn_mfma_f32_16x16x32_bf16((A), (B), (C), 0, 0, 0)

// triangle decode shared by pair_x / pair_l (must match exactly)
__device__ __forceinline__ void tri_decode(int bx, int& bm, int& bn) {
    int swz = (bx & 7) * 66 + (bx >> 3);        // 528 = 8*66 bijective XCD chunks
    int rem = swz, m = 0;
    while (rem >= 32 - m) { rem -= 32 - m; ++m; }
    bm = m; bn = m + rem;
}

// ---- split-precision GEMM: C = lrelu(A @ W^T + b), BM=128 BN=64 ----
// Depth-3 counted-vmcnt pipeline (3 LDS buffer sets, WAITV(6) steady state).
// 3-MFMA split: ah*bh + ah*bl + al*bh (residual ~2^-18 relative).
__global__ __launch_bounds__(256, 2) void gemm_lrelu(
    const __hip_bfloat16* __restrict__ Ah, const __hip_bfloat16* __restrict__ Al,
    const __hip_bfloat16* __restrict__ Wh, const __hip_bfloat16* __restrict__ Wl,
    const float* __restrict__ bias,
    float* __restrict__ Cf, __hip_bfloat16* __restrict__ Ch, __hip_bfloat16* __restrict__ Cl,
    float* __restrict__ sumsq, int N, int K)
{
    __shared__ short smem[36864];
    const int tid = threadIdx.x, lane = tid & 63, wave = tid >> 6;
    const int wm = wave >> 1, wn = wave & 1;
    const int bm = blockIdx.x, bn = blockIdx.y;
    const int nk = K >> 5;

    const int lr0 = wave * 32 + (lane >> 2), lr1 = lr0 + 16;
    const int lrW = wave * 16 + (lane >> 2);
    const int ts  = lane & 3;
    const int sa  = ts ^ ((lr0 >> 1) & 3);
    const int sw  = ts ^ ((lrW >> 1) & 3);

    const __hip_bfloat16* pAh0 = Ah + (size_t)(bm * 128 + lr0) * K + sa * 8;
    const __hip_bfloat16* pAh1 = Ah + (size_t)(bm * 128 + lr1) * K + sa * 8;
    const __hip_bfloat16* pAl0 = Al + (size_t)(bm * 128 + lr0) * K + sa * 8;
    const __hip_bfloat16* pAl1 = Al + (size_t)(bm * 128 + lr1) * K + sa * 8;
    const __hip_bfloat16* pWh0 = Wh + (size_t)(bn * 64 + lrW) * K + sw * 8;
    const __hip_bfloat16* pWl0 = Wl + (size_t)(bn * 64 + lrW) * K + sw * 8;

    short* dAh0 = smem + lr0 * 32 + ts * 8;
    short* dAh1 = smem + lr1 * 32 + ts * 8;
    short* dAl0 = smem + 12288 + lr0 * 32 + ts * 8;
    short* dAl1 = smem + 12288 + lr1 * 32 + ts * 8;
    short* dWh  = smem + 24576 + lrW * 32 + ts * 8;
    short* dWl  = smem + 30720 + lrW * 32 + ts * 8;

    const int rA = wm * 64 + (lane & 15);
    const int rB = wn * 32 + (lane & 15);
    const int pos = (lane >> 4) ^ ((lane >> 1) & 3);
    const short* baseA = smem + rA * 32 + pos * 8;            // Ah; Al at +12288
    const short* baseB = smem + 24576 + rB * 32 + pos * 8;    // Wh; Wl at +6144

    f32x4 acc[4][2] = {};

    auto STAGE = [&](int oA) {   // 6 gloads; oW = oA>>1
        int oW = oA >> 1;
        gload_lds16(pAh0, dAh0 + oA); gload_lds16(pAh1, dAh1 + oA);
        gload_lds16(pAl0, dAl0 + oA); gload_lds16(pAl1, dAl1 + oA);
        gload_lds16(pWh0, dWh + oW);  gload_lds16(pWl0, dWl + oW);
        pAh0 += 32; pAh1 += 32; pAl0 += 32; pAl1 += 32; pWh0 += 32; pWl0 += 32;
    };
    auto STEP = [&](int oA) {
        int oW = oA >> 1;
        bf16x8 ah[4], al[4], bh[2], bl[2];
#pragma unroll
        for (int m = 0; m < 4; ++m) {
            ah[m] = ldfrag(baseA + oA + m * 512);
            al[m] = ldfrag(baseA + 12288 + oA + m * 512);
        }
#pragma unroll
        for (int n = 0; n < 2; ++n) {
            bh[n] = ldfrag(baseB + oW + n * 512);
            bl[n] = ldfrag(baseB + 6144 + oW + n * 512);
        }
#pragma unroll
        for (int m = 0; m < 4; ++m)
#pragma unroll
            for (int n = 0; n < 2; ++n) {
                acc[m][n] = MFMA16(ah[m], bh[n], acc[m][n]);
                acc[m][n] = MFMA16(ah[m], bl[n], acc[m][n]);
                acc[m][n] = MFMA16(al[m], bh[n], acc[m][n]);
            }
    };

    STAGE(0); STAGE(4096);
    int oc = 0;
#pragma unroll 1
    for (int k = 0; k < nk - 1; ++k) {
        WAITV(6);
        BARRIER();
        int o2 = (oc == 0) ? 8192 : oc - 4096;
        if (k + 2 < nk) STAGE(o2);
        STEP(oc);
        oc = (oc == 8192) ? 0 : oc + 4096;
    }
    WAITV(0); BARRIER();
    STEP(oc);

    float bcol[2];
#pragma unroll
    for (int n = 0; n < 2; ++n) bcol[n] = bias[bn * 64 + wn * 32 + n * 16 + (lane & 15)];

#pragma unroll
    for (int m = 0; m < 4; ++m)
#pragma unroll
        for (int n = 0; n < 2; ++n)
#pragma unroll
            for (int j = 0; j < 4; ++j) {
                float v = acc[m][n][j] + bcol[n];
                acc[m][n][j] = v >= 0.f ? v : SLOPE * v;
            }
#pragma unroll
    for (int m = 0; m < 4; ++m)
#pragma unroll
        for (int n = 0; n < 2; ++n)
#pragma unroll
            for (int j = 0; j < 4; ++j) {
                int grow = bm * 128 + wm * 64 + m * 16 + (lane >> 4) * 4 + j;
                int gcol = bn * 64 + wn * 32 + n * 16 + (lane & 15);
                size_t idx = (size_t)grow * N + gcol;
                float v = acc[m][n][j];
                if (Cf) Cf[idx] = v;
                if (Ch) {
                    __hip_bfloat16 h = __float2bfloat16(v);
                    Ch[idx] = h;
                    Cl[idx] = __float2bfloat16(v - __bfloat162float(h));
                }
            }
    if (sumsq) {
#pragma unroll
        for (int m = 0; m < 4; ++m)
#pragma unroll
            for (int j = 0; j < 4; ++j) {
                float p = acc[m][0][j] * acc[m][0][j] + acc[m][1][j] * acc[m][1][j];
#pragma unroll
                for (int w = 1; w < 16; w <<= 1) p += __shfl_xor(p, w);
                if ((lane & 15) == 0) {
                    int grow = bm * 128 + wm * 64 + m * 16 + (lane >> 4) * 4 + j;
                    atomicAdd(&sumsq[grow], p);
                }
            }
    }
}

// ---- pair_x: X Gram -> d1; fold s1/s11; store packed-bf16 d1 tile ----
// Triangle 528 blocks. m97 shape: 4 waves, 64x64/wave, acc[4][4] ONLY.
// 3 LDS buf sets (48KB), depth-2-ahead, WAITV(4). No second accumulator epoch
// -> peak live ~110 VGPR -> honest fit under (256,3) cap, no spill.
__global__ __launch_bounds__(256, 3) void pair_x(
    const __hip_bfloat16* __restrict__ Xh, const float* __restrict__ r1,
    unsigned* __restrict__ d1buf, double* __restrict__ stats)
{
    int bm, bn; tri_decode(blockIdx.x, bm, bn);

    __shared__ short smem[24576];   // A@{0,4096,8192}, B@12288+{0,4096,8192}
    const int tid = threadIdx.x, lane = tid & 63, wave = tid >> 6;
    const int wm = wave >> 1, wn = wave & 1;

    const int lr0 = wave * 32 + (lane >> 2), lr1 = lr0 + 16;
    const int ts = lane & 3;
    const int sa = ts ^ ((lr0 >> 1) & 3);

    const __hip_bfloat16* pXa0 = Xh + (size_t)(bm * 128 + lr0) * D0 + sa * 8;
    const __hip_bfloat16* pXa1 = Xh + (size_t)(bm * 128 + lr1) * D0 + sa * 8;
    const __hip_bfloat16* pXb0 = Xh + (size_t)(bn * 128 + lr0) * D0 + sa * 8;
    const __hip_bfloat16* pXb1 = Xh + (size_t)(bn * 128 + lr1) * D0 + sa * 8;

    short* dA0 = smem + lr0 * 32 + ts * 8;
    short* dA1 = smem + lr1 * 32 + ts * 8;
    short* dB0 = smem + 12288 + lr0 * 32 + ts * 8;
    short* dB1 = smem + 12288 + lr1 * 32 + ts * 8;

    const int pos = (lane >> 4) ^ ((lane >> 1) & 3);
    const short* baseA = smem + (wm * 64 + (lane & 15)) * 32 + pos * 8;
    const short* baseB = smem + 12288 + (wn * 64 + (lane & 15)) * 32 + pos * 8;

    auto STAGEX = [&](int o) {   // 4 gloads per wave
        gload_lds16(pXa0, dA0 + o); gload_lds16(pXa1, dA1 + o);
        gload_lds16(pXb0, dB0 + o); gload_lds16(pXb1, dB1 + o);
        pXa0 += 32; pXa1 += 32; pXb0 += 32; pXb1 += 32;
    };

    f32x4 acc[4][4] = {};
    auto STEP = [&](int o) {
        bf16x8 a[4], b[4];
#pragma unroll
        for (int m = 0; m < 4; ++m) a[m] = ldfrag(baseA + o + m * 512);
#pragma unroll
        for (int n = 0; n < 4; ++n) b[n] = ldfrag(baseB + o + n * 512);
#pragma unroll
        for (int m = 0; m < 4; ++m)
#pragma unroll
            for (int n = 0; n < 4; ++n)
                acc[m][n] = MFMA16(a[m], b[n], acc[m][n]);
    };

    STAGEX(0); STAGEX(4096);                               // stages X0, X1
    WAITV(4); BARRIER(); STAGEX(8192); STEP(0);            // g=0, stage 2
    WAITV(4); BARRIER(); STAGEX(0);    STEP(4096);         // g=1, stage 3
#pragma unroll 1
    for (int k = 0; k < 9; ++k) {                          // g=2..28
        WAITV(4); BARRIER(); STAGEX(4096); STEP(8192);
        WAITV(4); BARRIER(); STAGEX(8192); STEP(0);
        WAITV(4); BARRIER(); STAGEX(0);    STEP(4096);
    }
    WAITV(4); BARRIER(); STAGEX(4096); STEP(8192);         // g=29, stage 31
    WAITV(4); BARRIER();               STEP(0);            // g=30
    WAITV(0); BARRIER();               STEP(4096);         // g=31

    // epilogue: distances, s1/s11, packed d1 store (coalesced across lanes)
    float r1i[4][4], r1j[4];
#pragma unroll
    for (int m = 0; m < 4; ++m)
#pragma unroll
        for (int j = 0; j < 4; ++j)
            r1i[m][j] = r1[bm * 128 + wm * 64 + m * 16 + (lane >> 4) * 4 + j];
#pragma unroll
    for (int n = 0; n < 4; ++n)
        r1j[n] = r1[bn * 128 + wn * 64 + n * 16 + (lane & 15)];

    unsigned* db = d1buf + (size_t)blockIdx.x * 8192;
    float s1 = 0.f, s11 = 0.f;
#pragma unroll
    for (int m = 0; m < 4; ++m)
#pragma unroll
        for (int n = 0; n < 4; ++n)
#pragma unroll
            for (int jj = 0; jj < 2; ++jj) {
                float dv[2];
#pragma unroll
                for (int h = 0; h < 2; ++h) {
                    int j = jj * 2 + h;
                    int gi = bm * 128 + wm * 64 + m * 16 + (lane >> 4) * 4 + j;
                    int gj = bn * 128 + wn * 64 + n * 16 + (lane & 15);
                    float sq = r1i[m][j] + r1j[n] - 2.0f * acc[m][n][j];
                    dv[h] = (gi == gj || sq <= 0.f) ? 0.f : sqrtf(sq);
                    s1 += dv[h]; s11 += dv[h] * dv[h];
                }
                db[((((wave * 4 + m) * 4 + n) * 2 + jj) << 6) + lane] = packbf2(dv[0], dv[1]);
            }

    float vals[2] = { s1, s11 };
#pragma unroll
    for (int q = 0; q < 2; ++q)
        for (int off = 32; off; off >>= 1) vals[q] += __shfl_down(vals[q], off);
    __syncthreads();
    float* red = (float*)smem;
    if (lane == 0) { red[wave * 2] = vals[0]; red[wave * 2 + 1] = vals[1]; }
    __syncthreads();
    if (tid == 0) {
        double w = (bm == bn) ? 1.0 : 2.0;
        double t0 = (double)red[0] + red[2] + red[4] + red[6];
        double t1 = (double)red[1] + red[3] + red[5] + red[7];
        atomicAdd(&stats[0], w * t0);   // s1
        atomicAdd(&stats[2], w * t1);   // s11
    }
}

// ---- pair_l: latent Gram -> d2; read packed d1; fold s2/s22/s12 ----
__global__ __launch_bounds__(256, 3) void pair_l(
    const __hip_bfloat16* __restrict__ Lh, const float* __restrict__ r2,
    const unsigned* __restrict__ d1buf, double* __restrict__ stats)
{
    int bm, bn; tri_decode(blockIdx.x, bm, bn);

    __shared__ short smem[24576];
    const int tid = threadIdx.x, lane = tid & 63, wave = tid >> 6;
    const int wm = wave >> 1, wn = wave & 1;

    const int lr0 = wave * 32 + (lane >> 2), lr1 = lr0 + 16;
    const int ts = lane & 3;
    const int sa = ts ^ ((lr0 >> 1) & 3);

    const __hip_bfloat16* qLa0 = Lh + (size_t)(bm * 128 + lr0) * DLAT + sa * 8;
    const __hip_bfloat16* qLa1 = Lh + (size_t)(bm * 128 + lr1) * DLAT + sa * 8;
    const __hip_bfloat16* qLb0 = Lh + (size_t)(bn * 128 + lr0) * DLAT + sa * 8;
    const __hip_bfloat16* qLb1 = Lh + (size_t)(bn * 128 + lr1) * DLAT + sa * 8;

    short* dA0 = smem + lr0 * 32 + ts * 8;
    short* dA1 = smem + lr1 * 32 + ts * 8;
    short* dB0 = smem + 12288 + lr0 * 32 + ts * 8;
    short* dB1 = smem + 12288 + lr1 * 32 + ts * 8;

    const int pos = (lane >> 4) ^ ((lane >> 1) & 3);
    const short* baseA = smem + (wm * 64 + (lane & 15)) * 32 + pos * 8;
    const short* baseB = smem + 12288 + (wn * 64 + (lane & 15)) * 32 + pos * 8;

    auto STAGEL = [&](int o) {
        gload_lds16(qLa0, dA0 + o); gload_lds16(qLa1, dA1 + o);
        gload_lds16(qLb0, dB0 + o); gload_lds16(qLb1, dB1 + o);
        qLa0 += 32; qLa1 += 32; qLb0 += 32; qLb1 += 32;
    };

    f32x4 acc2[4][4] = {};
    auto STEP = [&](int o) {
        bf16x8 a[4], b[4];
#pragma unroll
        for (int m = 0; m < 4; ++m) a[m] = ldfrag(baseA + o + m * 512);
#pragma unroll
        for (int n = 0; n < 4; ++n) b[n] = ldfrag(baseB + o + n * 512);
#pragma unroll
        for (int m = 0; m < 4; ++m)
#pragma unroll
            for (int n = 0; n < 4; ++n)
                acc2[m][n] = MFMA16(a[m], b[n], acc2[m][n]);
    };

    STAGEL(0); STAGEL(4096);
    WAITV(4); BARRIER(); STAGEL(8192); STEP(0);        // g=0, stage 2
    WAITV(4); BARRIER(); STAGEL(0);    STEP(4096);     // g=1, stage 3 -> buf0
    WAITV(4); BARRIER();               STEP(8192);     // g=2
    WAITV(0); BARRIER();               STEP(0);        // g=3

    float r2i[4][4], r2j[4];
#pragma unroll
    for (int m = 0; m < 4; ++m)
#pragma unroll
        for (int j = 0; j < 4; ++j)
            r2i[m][j] = r2[bm * 128 + wm * 64 + m * 16 + (lane >> 4) * 4 + j];
#pragma unroll
    for (int n = 0; n < 4; ++n)
        r2j[n] = r2[bn * 128 + wn * 64 + n * 16 + (lane & 15)];

    const unsigned* db = d1buf + (size_t)blockIdx.x * 8192;
    float s2 = 0.f, s22 = 0.f, s12 = 0.f;
#pragma unroll
    for (int m = 0; m < 4; ++m)
#pragma unroll
        for (int n = 0; n < 4; ++n)
#pragma unroll
            for (int jj = 0; jj < 2; ++jj) {
                unsigned pk = db[((((wave * 4 + m) * 4 + n) * 2 + jj) << 6) + lane];
#pragma unroll
                for (int h = 0; h < 2; ++h) {
                    int j = jj * 2 + h;
                    int gi = bm * 128 + wm * 64 + m * 16 + (lane >> 4) * 4 + j;
                    int gj = bn * 128 + wn * 64 + n * 16 + (lane & 15);
                    float sq2 = r2i[m][j] + r2j[n] - 2.0f * acc2[m][n][j];
                    float d2v = (gi == gj || sq2 <= 0.f) ? 0.f : sqrtf(sq2);
                    float d1v = unpackbf(pk, h);
                    s2 += d2v; s22 += d2v * d2v; s12 += d1v * d2v;
                }
            }

    float vals[3] = { s2, s22, s12 };
#pragma unroll
    for (int q = 0; q < 3; ++q)
        for (int off = 32; off; off >>= 1) vals[q] += __shfl_down(vals[q], off);
    __syncthreads();
    float* red = (float*)smem;
    if (lane == 0) {
#pragma unroll
        for (int q = 0; q < 3; ++q) red[wave * 3 + q] = vals[q];
    }
    __syncthreads();
    if (tid == 0) {
        double w = (bm == bn) ? 1.0 : 2.0;
        double t0 = (double)red[0] + red[3] + red[6] + red[9];
        double t1 = (double)red[1] + red[4] + red[7] + red[10];
        double t2 = (double)red[2] + red[5] + red[8] + red[11];
        atomicAdd(&stats[1], w * t0);   // s2
        atomicAdd(&stats[3], w * t1);   // s22
        atomicAdd(&stats[4], w * t2);   // s12
    }
}

// ---- fused hi/lo split for x + all 6 weights; also r1 = rowsumsq(x) ----
struct SplitSeg { const float* src; __hip_bfloat16* hi; __hip_bfloat16* lo; };
struct SplitArgs { SplitSeg s[7]; unsigned cum4[8]; };

__global__ void split_many(SplitArgs A, int total4, float* __restrict__ r1) {
    int v = blockIdx.x * blockDim.x + threadIdx.x;
    if (v >= total4) return;
    int si = 0;
#pragma unroll
    for (int i = 1; i < 7; ++i) si = (v >= (int)A.cum4[i]) ? i : si;
    int local = v - (int)A.cum4[si];
    float4 f = *(const float4*)(A.s[si].src + (size_t)local * 4);
    float fv[4] = { f.x, f.y, f.z, f.w };
    __hip_bfloat16* hi = A.s[si].hi;
    __hip_bfloat16* lo = A.s[si].lo;
#pragma unroll
    for (int j = 0; j < 4; ++j) {
        __hip_bfloat16 h = __float2bfloat16(fv[j]);
        hi[local * 4 + j] = h;
        lo[local * 4 + j] = __float2bfloat16(fv[j] - __bfloat162float(h));
    }
    if (blockIdx.x < 4096) {   // pure-x block == one row of x
        float s = fv[0]*fv[0] + fv[1]*fv[1] + fv[2]*fv[2] + fv[3]*fv[3];
        for (int off = 32; off; off >>= 1) s += __shfl_down(s, off);
        __shared__ float red[4];
        int lane = threadIdx.x & 63, wave = threadIdx.x >> 6;
        if (lane == 0) red[wave] = s;
        __syncthreads();
        if (threadIdx.x == 0) r1[blockIdx.x] = red[0] + red[1] + red[2] + red[3];
    }
}

__global__ void finalize_corr(const double* __restrict__ stats, float* __restrict__ corr_out) {
    double n = (double)NROW * (double)NROW;
    double s1 = stats[0], s2 = stats[1], s11 = stats[2], s22 = stats[3], s12 = stats[4];
    double m1 = s1 / n, m2 = s2 / n;
    double cov = s12 / n - m1 * m2;                  // biased (mean)
    double v1 = (s11 - n * m1 * m1) / (n - 1.0);     // unbiased (ddof=1)
    double v2 = (s22 - n * m2 * m2) / (n - 1.0);
    corr_out[0] = (float)(cov / sqrt(v1 * v2));
}

extern "C" void kernel_launch(void* const* d_in, const int* in_sizes, int n_in,
                              void* d_out, int out_size, void* d_ws, size_t ws_size,
                              hipStream_t stream) {
    const float* x   = (const float*)d_in[0];
    const float* We1 = (const float*)d_in[1];  const float* be1 = (const float*)d_in[2];
    const float* We2 = (const float*)d_in[3];  const float* be2 = (const float*)d_in[4];
    const float* We3 = (const float*)d_in[5];  const float* be3 = (const float*)d_in[6];
    const float* Wd1 = (const float*)d_in[7];  const float* bd1 = (const float*)d_in[8];
    const float* Wd2 = (const float*)d_in[9];  const float* bd2 = (const float*)d_in[10];
    const float* Wd3 = (const float*)d_in[11]; const float* bd3 = (const float*)d_in[12];
    float* out = (float*)d_out;

    char* ws = (char*)d_ws;
    size_t off = 0;
    auto alloc = [&](size_t bytes) -> char* {
        char* p = ws + off; off += (bytes + 255) & ~(size_t)255; return p;
    };
    typedef __hip_bfloat16 bf;
    bf* xh  = (bf*)alloc((size_t)NROW * D0 * 2);   bf* xl  = (bf*)alloc((size_t)NROW * D0 * 2);
    bf* w1h = (bf*)alloc((size_t)DH1 * D0 * 2);    bf* w1l = (bf*)alloc((size_t)DH1 * D0 * 2);
    bf* w2h = (bf*)alloc((size_t)DH2 * DH1 * 2);   bf* w2l = (bf*)alloc((size_t)DH2 * DH1 * 2);
    bf* w3h = (bf*)alloc((size_t)DLAT * DH2 * 2);  bf* w3l = (bf*)alloc((size_t)DLAT * DH2 * 2);
    bf* w4h = (bf*)alloc((size_t)DH2 * DLAT * 2);  bf* w4l = (bf*)alloc((size_t)DH2 * DLAT * 2);
    bf* w5h = (bf*)alloc((size_t)DH1 * DH2 * 2);   bf* w5l = (bf*)alloc((size_t)DH1 * DH2 * 2);
    bf* w6h = (bf*)alloc((size_t)D0 * DH1 * 2);    bf* w6l = (bf*)alloc((size_t)D0 * DH1 * 2);
    bf* h1h = (bf*)alloc((size_t)NROW * DH1 * 2);  bf* h1l = (bf*)alloc((size_t)NROW * DH1 * 2);
    bf* h2h = (bf*)alloc((size_t)NROW * DH2 * 2);  bf* h2l = (bf*)alloc((size_t)NROW * DH2 * 2);
    bf* lth = (bf*)alloc((size_t)NROW * DLAT * 2); bf* ltl = (bf*)alloc((size_t)NROW * DLAT * 2);
    bf* d4h = (bf*)alloc((size_t)NROW * DH2 * 2);  bf* d4l = (bf*)alloc((size_t)NROW * DH2 * 2);
    bf* d5h = (bf*)alloc((size_t)NROW * DH1 * 2);  bf* d5l = (bf*)alloc((size_t)NROW * DH1 * 2);
    float* r1v = (float*)alloc((size_t)NROW * 4);
    float* r2v = (float*)alloc((size_t)NROW * 4);      // 16384 B, 256-aligned
    double* stats = (double*)alloc(5 * 8);             // contiguous after r2v
    unsigned* d1buf = (unsigned*)alloc((size_t)528 * 8192 * 4);   // 17.3 MB packed d1

    // zero r2v + stats in one async memset (graph-capture safe)
    hipMemsetAsync(r2v, 0, (size_t)NROW * 4 + 256, stream);

    SplitArgs SA;
    const float* srcs[7] = { x, We1, We2, We3, Wd1, Wd2, Wd3 };
    bf* his[7] = { xh, w1h, w2h, w3h, w4h, w5h, w6h };
    bf* los[7] = { xl, w1l, w2l, w3l, w4l, w5l, w6l };
    unsigned ns[7] = { NROW * D0, DH1 * D0, DH2 * DH1, DLAT * DH2,
                       DH2 * DLAT, DH1 * DH2, D0 * DH1 };
    unsigned cum = 0;
    for (int i = 0; i < 7; ++i) {
        SA.s[i].src = srcs[i]; SA.s[i].hi = his[i]; SA.s[i].lo = los[i];
        SA.cum4[i] = cum; cum += ns[i] / 4;
    }
    SA.cum4[7] = cum;
    split_many<<<(cum + 255) / 256, 256, 0, stream>>>(SA, (int)cum, r1v);

    // X-distance statistics (only needs xh, r1v) — runs before the MLP chain
    pair_x<<<dim3(528), 256, 0, stream>>>(xh, r1v, d1buf, stats);

    // encoder
    gemm_lrelu<<<dim3(NROW / 128, DH1 / 64), 256, 0, stream>>>(
        xh, xl, w1h, w1l, be1, nullptr, h1h, h1l, nullptr, DH1, D0);
    gemm_lrelu<<<dim3(NROW / 128, DH2 / 64), 256, 0, stream>>>(
        h1h, h1l, w2h, w2l, be2, nullptr, h2h, h2l, nullptr, DH2, DH1);
    gemm_lrelu<<<dim3(NROW / 128, DLAT / 64), 256, 0, stream>>>(
        h2h, h2l, w3h, w3l, be3, nullptr, lth, ltl, r2v, DLAT, DH2);
    // decoder
    gemm_lrelu<<<dim3(NROW / 128, DH2 / 64), 256, 0, stream>>>(
        lth, ltl, w4h, w4l, bd1, nullptr, d4h, d4l, nullptr, DH2, DLAT);
    gemm_lrelu<<<dim3(NROW / 128, DH1 / 64), 256, 0, stream>>>(
        d4h, d4l, w5h, w5l, bd2, nullptr, d5h, d5l, nullptr, DH1, DH2);
    gemm_lrelu<<<dim3(NROW / 128, D0 / 64), 256, 0, stream>>>(
        d5h, d5l, w6h, w6l, bd3, out, nullptr, nullptr, nullptr, D0, DH1);

    // latent-distance statistics + cross term
    pair_l<<<dim3(528), 256, 0, stream>>>(lth, r2v, d1buf, stats);
    finalize_corr<<<1, 1, 0, stream>>>(stats, out + (size_t)NROW * D0);
}

// Round 11
// 240.916 us; speedup vs baseline: 1.2142x; 1.0152x over previous
//
#include <hip/hip_runtime.h>
#include <hip/hip_bf16.h>

#define NROW 4096
#define D0   1024
#define DH1  512
#define DH2  256
#define DLAT 128
#define SLOPE 0.01f

typedef float f32x4 __attribute__((ext_vector_type(4)));
typedef __bf16 bf16x8 __attribute__((ext_vector_type(8)));
typedef short short8 __attribute__((ext_vector_type(8)));

#define WAITV(N) asm volatile("s_waitcnt vmcnt(" #N ")" ::: "memory")
#define BARRIER() do { __builtin_amdgcn_s_barrier(); __builtin_amdgcn_sched_barrier(0); } while (0)

// ---- async global->LDS 16B (wave-uniform base + lane*16 dest) ----
__device__ __forceinline__ void gload_lds16(const void* gp, void* lp) {
    __builtin_amdgcn_global_load_lds(
        (const __attribute__((address_space(1))) void*)(unsigned long long)gp,
        (__attribute__((address_space(3))) void*)(unsigned int)(unsigned long long)lp,
        16, 0, 0);
}

__device__ __forceinline__ bf16x8 ldfrag(const short* p) {
    union { short8 s; bf16x8 b; } u;
    u.s = *reinterpret_cast<const short8*>(p);
    return u.b;
}

__device__ __forceinline__ unsigned packbf2(float a, float b) {
    union { __hip_bfloat16 h; unsigned short u; } ua, ub;
    ua.h = __float2bfloat16(a); ub.h = __float2bfloat16(b);
    return (unsigned)ua.u | ((unsigned)ub.u << 16);
}
__device__ __forceinline__ float unpackbf(unsigned p, int hi) {
    union { unsigned short u; __hip_bfloat16 h; } t;
    t.u = (unsigned short)(hi ? (p >> 16) : p);
    return __bfloat162float(t.h);
}

#define MFMA16(A, B, C) __builtin_amdgcn_mfma_f32_16x16x32_bf16((A), (B), (C), 0, 0, 0)

// triangle decode shared by pair_x / pair_l (must match exactly)
__device__ __forceinline__ void tri_decode(int bx, int& bm, int& bn) {
    int swz = (bx & 7) * 66 + (bx >> 3);        // 528 = 8*66 bijective XCD chunks
    int rem = swz, m = 0;
    while (rem >= 32 - m) { rem -= 32 - m; ++m; }
    bm = m; bn = m + rem;
}

// ---- split-precision GEMM v2: BM=64 BN=64, 4 waves (2x2, 32x32/wave) ----
// 2-buffer depth-2 parity pipeline, 32 KB LDS, 4 blocks/CU capacity.
// Grids: every layer gets >=128 blocks; L1:512 L2:256 L3:128 L4:256 L5:512 L6:1024.
// 3-MFMA split: ah*bh + ah*bl + al*bh (residual ~2^-18 relative).
// LDS per buf (shorts): Ah@0 Al@2048 Bh@4096 Bl@6144; buf1 at +8192.
__global__ __launch_bounds__(256, 4) void gemm_lrelu(
    const __hip_bfloat16* __restrict__ Ah, const __hip_bfloat16* __restrict__ Al,
    const __hip_bfloat16* __restrict__ Wh, const __hip_bfloat16* __restrict__ Wl,
    const float* __restrict__ bias,
    float* __restrict__ Cf, __hip_bfloat16* __restrict__ Ch, __hip_bfloat16* __restrict__ Cl,
    float* __restrict__ sumsq, int N, int K)
{
    __shared__ short smem[16384];
    const int tid = threadIdx.x, lane = tid & 63, wave = tid >> 6;
    const int wm = wave >> 1, wn = wave & 1;
    const int bm = blockIdx.x, bn = blockIdx.y;
    const int nk = K >> 5;              // 4 / 8 / 16 / 32 — always even

    const int lr = wave * 16 + (lane >> 2);       // rows 0..63, 16/wave
    const int ts = lane & 3;
    const int sa = ts ^ ((lr >> 1) & 3);

    const __hip_bfloat16* pAh = Ah + (size_t)(bm * 64 + lr) * K + sa * 8;
    const __hip_bfloat16* pAl = Al + (size_t)(bm * 64 + lr) * K + sa * 8;
    const __hip_bfloat16* pWh = Wh + (size_t)(bn * 64 + lr) * K + sa * 8;
    const __hip_bfloat16* pWl = Wl + (size_t)(bn * 64 + lr) * K + sa * 8;

    short* dAh = smem + lr * 32 + ts * 8;
    short* dAl = smem + 2048 + lr * 32 + ts * 8;
    short* dWh = smem + 4096 + lr * 32 + ts * 8;
    short* dWl = smem + 6144 + lr * 32 + ts * 8;

    const int pos = (lane >> 4) ^ ((lane >> 1) & 3);
    const short* baseA = smem + (wm * 32 + (lane & 15)) * 32 + pos * 8;   // Ah; Al at +2048
    const short* baseB = smem + 4096 + (wn * 32 + (lane & 15)) * 32 + pos * 8;  // Wh; Wl at +2048

    f32x4 acc[2][2] = {};

    auto STAGE = [&](int o) {   // 4 gloads per wave
        gload_lds16(pAh, dAh + o); gload_lds16(pAl, dAl + o);
        gload_lds16(pWh, dWh + o); gload_lds16(pWl, dWl + o);
        pAh += 32; pAl += 32; pWh += 32; pWl += 32;
    };
    auto STEP = [&](int o) {
        bf16x8 ah[2], al[2], bh[2], bl[2];
#pragma unroll
        for (int m = 0; m < 2; ++m) {
            ah[m] = ldfrag(baseA + o + m * 512);
            al[m] = ldfrag(baseA + 2048 + o + m * 512);
        }
#pragma unroll
        for (int n = 0; n < 2; ++n) {
            bh[n] = ldfrag(baseB + o + n * 512);
            bl[n] = ldfrag(baseB + 2048 + o + n * 512);
        }
#pragma unroll
        for (int m = 0; m < 2; ++m)
#pragma unroll
            for (int n = 0; n < 2; ++n) {
                acc[m][n] = MFMA16(ah[m], bh[n], acc[m][n]);
                acc[m][n] = MFMA16(ah[m], bl[n], acc[m][n]);
                acc[m][n] = MFMA16(al[m], bh[n], acc[m][n]);
            }
    };

    STAGE(0);
#pragma unroll 1
    for (int k2 = 0; k2 < (nk >> 1) - 1; ++k2) {
        WAITV(0); BARRIER(); STAGE(8192); STEP(0);
        WAITV(0); BARRIER(); STAGE(0);    STEP(8192);
    }
    WAITV(0); BARRIER(); STAGE(8192); STEP(0);
    WAITV(0); BARRIER();              STEP(8192);

    float bcol[2];
#pragma unroll
    for (int n = 0; n < 2; ++n) bcol[n] = bias[bn * 64 + wn * 32 + n * 16 + (lane & 15)];

#pragma unroll
    for (int m = 0; m < 2; ++m)
#pragma unroll
        for (int n = 0; n < 2; ++n)
#pragma unroll
            for (int j = 0; j < 4; ++j) {
                float v = acc[m][n][j] + bcol[n];
                acc[m][n][j] = v >= 0.f ? v : SLOPE * v;
            }
#pragma unroll
    for (int m = 0; m < 2; ++m)
#pragma unroll
        for (int n = 0; n < 2; ++n)
#pragma unroll
            for (int j = 0; j < 4; ++j) {
                int grow = bm * 64 + wm * 32 + m * 16 + (lane >> 4) * 4 + j;
                int gcol = bn * 64 + wn * 32 + n * 16 + (lane & 15);
                size_t idx = (size_t)grow * N + gcol;
                float v = acc[m][n][j];
                if (Cf) Cf[idx] = v;
                if (Ch) {
                    __hip_bfloat16 h = __float2bfloat16(v);
                    Ch[idx] = h;
                    Cl[idx] = __float2bfloat16(v - __bfloat162float(h));
                }
            }
    if (sumsq) {
#pragma unroll
        for (int m = 0; m < 2; ++m)
#pragma unroll
            for (int j = 0; j < 4; ++j) {
                float p = acc[m][0][j] * acc[m][0][j] + acc[m][1][j] * acc[m][1][j];
#pragma unroll
                for (int w = 1; w < 16; w <<= 1) p += __shfl_xor(p, w);
                if ((lane & 15) == 0) {
                    int grow = bm * 64 + wm * 32 + m * 16 + (lane >> 4) * 4 + j;
                    atomicAdd(&sumsq[grow], p);
                }
            }
    }
}

// ---- pair_x: X Gram -> d1; fold s1/s11; store packed-bf16 d1 tile ----
// Triangle 528 blocks. m97 shape: 4 waves, 64x64/wave, acc[4][4] ONLY.
// 3 LDS buf sets (48KB), depth-2-ahead, WAITV(4).
__global__ __launch_bounds__(256, 3) void pair_x(
    const __hip_bfloat16* __restrict__ Xh, const float* __restrict__ r1,
    unsigned* __restrict__ d1buf, double* __restrict__ stats)
{
    int bm, bn; tri_decode(blockIdx.x, bm, bn);

    __shared__ short smem[24576];   // A@{0,4096,8192}, B@12288+{0,4096,8192}
    const int tid = threadIdx.x, lane = tid & 63, wave = tid >> 6;
    const int wm = wave >> 1, wn = wave & 1;

    const int lr0 = wave * 32 + (lane >> 2), lr1 = lr0 + 16;
    const int ts = lane & 3;
    const int sa = ts ^ ((lr0 >> 1) & 3);

    const __hip_bfloat16* pXa0 = Xh + (size_t)(bm * 128 + lr0) * D0 + sa * 8;
    const __hip_bfloat16* pXa1 = Xh + (size_t)(bm * 128 + lr1) * D0 + sa * 8;
    const __hip_bfloat16* pXb0 = Xh + (size_t)(bn * 128 + lr0) * D0 + sa * 8;
    const __hip_bfloat16* pXb1 = Xh + (size_t)(bn * 128 + lr1) * D0 + sa * 8;

    short* dA0 = smem + lr0 * 32 + ts * 8;
    short* dA1 = smem + lr1 * 32 + ts * 8;
    short* dB0 = smem + 12288 + lr0 * 32 + ts * 8;
    short* dB1 = smem + 12288 + lr1 * 32 + ts * 8;

    const int pos = (lane >> 4) ^ ((lane >> 1) & 3);
    const short* baseA = smem + (wm * 64 + (lane & 15)) * 32 + pos * 8;
    const short* baseB = smem + 12288 + (wn * 64 + (lane & 15)) * 32 + pos * 8;

    auto STAGEX = [&](int o) {   // 4 gloads per wave
        gload_lds16(pXa0, dA0 + o); gload_lds16(pXa1, dA1 + o);
        gload_lds16(pXb0, dB0 + o); gload_lds16(pXb1, dB1 + o);
        pXa0 += 32; pXa1 += 32; pXb0 += 32; pXb1 += 32;
    };

    f32x4 acc[4][4] = {};
    auto STEP = [&](int o) {
        bf16x8 a[4], b[4];
#pragma unroll
        for (int m = 0; m < 4; ++m) a[m] = ldfrag(baseA + o + m * 512);
#pragma unroll
        for (int n = 0; n < 4; ++n) b[n] = ldfrag(baseB + o + n * 512);
#pragma unroll
        for (int m = 0; m < 4; ++m)
#pragma unroll
            for (int n = 0; n < 4; ++n)
                acc[m][n] = MFMA16(a[m], b[n], acc[m][n]);
    };

    STAGEX(0); STAGEX(4096);                               // stages X0, X1
    WAITV(4); BARRIER(); STAGEX(8192); STEP(0);            // g=0, stage 2
    WAITV(4); BARRIER(); STAGEX(0);    STEP(4096);         // g=1, stage 3
#pragma unroll 1
    for (int k = 0; k < 9; ++k) {                          // g=2..28
        WAITV(4); BARRIER(); STAGEX(4096); STEP(8192);
        WAITV(4); BARRIER(); STAGEX(8192); STEP(0);
        WAITV(4); BARRIER(); STAGEX(0);    STEP(4096);
    }
    WAITV(4); BARRIER(); STAGEX(4096); STEP(8192);         // g=29, stage 31
    WAITV(4); BARRIER();               STEP(0);            // g=30
    WAITV(0); BARRIER();               STEP(4096);         // g=31

    // epilogue: distances, s1/s11, packed d1 store (coalesced across lanes)
    float r1i[4][4], r1j[4];
#pragma unroll
    for (int m = 0; m < 4; ++m)
#pragma unroll
        for (int j = 0; j < 4; ++j)
            r1i[m][j] = r1[bm * 128 + wm * 64 + m * 16 + (lane >> 4) * 4 + j];
#pragma unroll
    for (int n = 0; n < 4; ++n)
        r1j[n] = r1[bn * 128 + wn * 64 + n * 16 + (lane & 15)];

    unsigned* db = d1buf + (size_t)blockIdx.x * 8192;
    float s1 = 0.f, s11 = 0.f;
#pragma unroll
    for (int m = 0; m < 4; ++m)
#pragma unroll
        for (int n = 0; n < 4; ++n)
#pragma unroll
            for (int jj = 0; jj < 2; ++jj) {
                float dv[2];
#pragma unroll
                for (int h = 0; h < 2; ++h) {
                    int j = jj * 2 + h;
                    int gi = bm * 128 + wm * 64 + m * 16 + (lane >> 4) * 4 + j;
                    int gj = bn * 128 + wn * 64 + n * 16 + (lane & 15);
                    float sq = r1i[m][j] + r1j[n] - 2.0f * acc[m][n][j];
                    dv[h] = (gi == gj || sq <= 0.f) ? 0.f : sqrtf(sq);
                    s1 += dv[h]; s11 += dv[h] * dv[h];
                }
                db[((((wave * 4 + m) * 4 + n) * 2 + jj) << 6) + lane] = packbf2(dv[0], dv[1]);
            }

    float vals[2] = { s1, s11 };
#pragma unroll
    for (int q = 0; q < 2; ++q)
        for (int off = 32; off; off >>= 1) vals[q] += __shfl_down(vals[q], off);
    __syncthreads();
    float* red = (float*)smem;
    if (lane == 0) { red[wave * 2] = vals[0]; red[wave * 2 + 1] = vals[1]; }
    __syncthreads();
    if (tid == 0) {
        double w = (bm == bn) ? 1.0 : 2.0;
        double t0 = (double)red[0] + red[2] + red[4] + red[6];
        double t1 = (double)red[1] + red[3] + red[5] + red[7];
        atomicAdd(&stats[0], w * t0);   // s1
        atomicAdd(&stats[2], w * t1);   // s11
    }
}

// ---- pair_l: latent Gram -> d2; read packed d1; fold s2/s22/s12 ----
__global__ __launch_bounds__(256, 3) void pair_l(
    const __hip_bfloat16* __restrict__ Lh, const float* __restrict__ r2,
    const unsigned* __restrict__ d1buf, double* __restrict__ stats)
{
    int bm, bn; tri_decode(blockIdx.x, bm, bn);

    __shared__ short smem[24576];
    const int tid = threadIdx.x, lane = tid & 63, wave = tid >> 6;
    const int wm = wave >> 1, wn = wave & 1;

    const int lr0 = wave * 32 + (lane >> 2), lr1 = lr0 + 16;
    const int ts = lane & 3;
    const int sa = ts ^ ((lr0 >> 1) & 3);

    const __hip_bfloat16* qLa0 = Lh + (size_t)(bm * 128 + lr0) * DLAT + sa * 8;
    const __hip_bfloat16* qLa1 = Lh + (size_t)(bm * 128 + lr1) * DLAT + sa * 8;
    const __hip_bfloat16* qLb0 = Lh + (size_t)(bn * 128 + lr0) * DLAT + sa * 8;
    const __hip_bfloat16* qLb1 = Lh + (size_t)(bn * 128 + lr1) * DLAT + sa * 8;

    short* dA0 = smem + lr0 * 32 + ts * 8;
    short* dA1 = smem + lr1 * 32 + ts * 8;
    short* dB0 = smem + 12288 + lr0 * 32 + ts * 8;
    short* dB1 = smem + 12288 + lr1 * 32 + ts * 8;

    const int pos = (lane >> 4) ^ ((lane >> 1) & 3);
    const short* baseA = smem + (wm * 64 + (lane & 15)) * 32 + pos * 8;
    const short* baseB = smem + 12288 + (wn * 64 + (lane & 15)) * 32 + pos * 8;

    auto STAGEL = [&](int o) {
        gload_lds16(qLa0, dA0 + o); gload_lds16(qLa1, dA1 + o);
        gload_lds16(qLb0, dB0 + o); gload_lds16(qLb1, dB1 + o);
        qLa0 += 32; qLa1 += 32; qLb0 += 32; qLb1 += 32;
    };

    f32x4 acc2[4][4] = {};
    auto STEP = [&](int o) {
        bf16x8 a[4], b[4];
#pragma unroll
        for (int m = 0; m < 4; ++m) a[m] = ldfrag(baseA + o + m * 512);
#pragma unroll
        for (int n = 0; n < 4; ++n) b[n] = ldfrag(baseB + o + n * 512);
#pragma unroll
        for (int m = 0; m < 4; ++m)
#pragma unroll
            for (int n = 0; n < 4; ++n)
                acc2[m][n] = MFMA16(a[m], b[n], acc2[m][n]);
    };

    STAGEL(0); STAGEL(4096);
    WAITV(4); BARRIER(); STAGEL(8192); STEP(0);        // g=0, stage 2
    WAITV(4); BARRIER(); STAGEL(0);    STEP(4096);     // g=1, stage 3 -> buf0
    WAITV(4); BARRIER();               STEP(8192);     // g=2
    WAITV(0); BARRIER();               STEP(0);        // g=3

    float r2i[4][4], r2j[4];
#pragma unroll
    for (int m = 0; m < 4; ++m)
#pragma unroll
        for (int j = 0; j < 4; ++j)
            r2i[m][j] = r2[bm * 128 + wm * 64 + m * 16 + (lane >> 4) * 4 + j];
#pragma unroll
    for (int n = 0; n < 4; ++n)
        r2j[n] = r2[bn * 128 + wn * 64 + n * 16 + (lane & 15)];

    const unsigned* db = d1buf + (size_t)blockIdx.x * 8192;
    float s2 = 0.f, s22 = 0.f, s12 = 0.f;
#pragma unroll
    for (int m = 0; m < 4; ++m)
#pragma unroll
        for (int n = 0; n < 4; ++n)
#pragma unroll
            for (int jj = 0; jj < 2; ++jj) {
                unsigned pk = db[((((wave * 4 + m) * 4 + n) * 2 + jj) << 6) + lane];
#pragma unroll
                for (int h = 0; h < 2; ++h) {
                    int j = jj * 2 + h;
                    int gi = bm * 128 + wm * 64 + m * 16 + (lane >> 4) * 4 + j;
                    int gj = bn * 128 + wn * 64 + n * 16 + (lane & 15);
                    float sq2 = r2i[m][j] + r2j[n] - 2.0f * acc2[m][n][j];
                    float d2v = (gi == gj || sq2 <= 0.f) ? 0.f : sqrtf(sq2);
                    float d1v = unpackbf(pk, h);
                    s2 += d2v; s22 += d2v * d2v; s12 += d1v * d2v;
                }
            }

    float vals[3] = { s2, s22, s12 };
#pragma unroll
    for (int q = 0; q < 3; ++q)
        for (int off = 32; off; off >>= 1) vals[q] += __shfl_down(vals[q], off);
    __syncthreads();
    float* red = (float*)smem;
    if (lane == 0) {
#pragma unroll
        for (int q = 0; q < 3; ++q) red[wave * 3 + q] = vals[q];
    }
    __syncthreads();
    if (tid == 0) {
        double w = (bm == bn) ? 1.0 : 2.0;
        double t0 = (double)red[0] + red[3] + red[6] + red[9];
        double t1 = (double)red[1] + red[4] + red[7] + red[10];
        double t2 = (double)red[2] + red[5] + red[8] + red[11];
        atomicAdd(&stats[1], w * t0);   // s2
        atomicAdd(&stats[3], w * t1);   // s22
        atomicAdd(&stats[4], w * t2);   // s12
    }
}

// ---- fused hi/lo split for x + all 6 weights; also r1 = rowsumsq(x) ----
struct SplitSeg { const float* src; __hip_bfloat16* hi; __hip_bfloat16* lo; };
struct SplitArgs { SplitSeg s[7]; unsigned cum4[8]; };

__global__ void split_many(SplitArgs A, int total4, float* __restrict__ r1) {
    int v = blockIdx.x * blockDim.x + threadIdx.x;
    if (v >= total4) return;
    int si = 0;
#pragma unroll
    for (int i = 1; i < 7; ++i) si = (v >= (int)A.cum4[i]) ? i : si;
    int local = v - (int)A.cum4[si];
    float4 f = *(const float4*)(A.s[si].src + (size_t)local * 4);
    float fv[4] = { f.x, f.y, f.z, f.w };
    __hip_bfloat16* hi = A.s[si].hi;
    __hip_bfloat16* lo = A.s[si].lo;
#pragma unroll
    for (int j = 0; j < 4; ++j) {
        __hip_bfloat16 h = __float2bfloat16(fv[j]);
        hi[local * 4 + j] = h;
        lo[local * 4 + j] = __float2bfloat16(fv[j] - __bfloat162float(h));
    }
    if (blockIdx.x < 4096) {   // pure-x block == one row of x
        float s = fv[0]*fv[0] + fv[1]*fv[1] + fv[2]*fv[2] + fv[3]*fv[3];
        for (int off = 32; off; off >>= 1) s += __shfl_down(s, off);
        __shared__ float red[4];
        int lane = threadIdx.x & 63, wave = threadIdx.x >> 6;
        if (lane == 0) red[wave] = s;
        __syncthreads();
        if (threadIdx.x == 0) r1[blockIdx.x] = red[0] + red[1] + red[2] + red[3];
    }
}

__global__ void finalize_corr(const double* __restrict__ stats, float* __restrict__ corr_out) {
    double n = (double)NROW * (double)NROW;
    double s1 = stats[0], s2 = stats[1], s11 = stats[2], s22 = stats[3], s12 = stats[4];
    double m1 = s1 / n, m2 = s2 / n;
    double cov = s12 / n - m1 * m2;                  // biased (mean)
    double v1 = (s11 - n * m1 * m1) / (n - 1.0);     // unbiased (ddof=1)
    double v2 = (s22 - n * m2 * m2) / (n - 1.0);
    corr_out[0] = (float)(cov / sqrt(v1 * v2));
}

extern "C" void kernel_launch(void* const* d_in, const int* in_sizes, int n_in,
                              void* d_out, int out_size, void* d_ws, size_t ws_size,
                              hipStream_t stream) {
    const float* x   = (const float*)d_in[0];
    const float* We1 = (const float*)d_in[1];  const float* be1 = (const float*)d_in[2];
    const float* We2 = (const float*)d_in[3];  const float* be2 = (const float*)d_in[4];
    const float* We3 = (const float*)d_in[5];  const float* be3 = (const float*)d_in[6];
    const float* Wd1 = (const float*)d_in[7];  const float* bd1 = (const float*)d_in[8];
    const float* Wd2 = (const float*)d_in[9];  const float* bd2 = (const float*)d_in[10];
    const float* Wd3 = (const float*)d_in[11]; const float* bd3 = (const float*)d_in[12];
    float* out = (float*)d_out;

    char* ws = (char*)d_ws;
    size_t off = 0;
    auto alloc = [&](size_t bytes) -> char* {
        char* p = ws + off; off += (bytes + 255) & ~(size_t)255; return p;
    };
    typedef __hip_bfloat16 bf;
    bf* xh  = (bf*)alloc((size_t)NROW * D0 * 2);   bf* xl  = (bf*)alloc((size_t)NROW * D0 * 2);
    bf* w1h = (bf*)alloc((size_t)DH1 * D0 * 2);    bf* w1l = (bf*)alloc((size_t)DH1 * D0 * 2);
    bf* w2h = (bf*)alloc((size_t)DH2 * DH1 * 2);   bf* w2l = (bf*)alloc((size_t)DH2 * DH1 * 2);
    bf* w3h = (bf*)alloc((size_t)DLAT * DH2 * 2);  bf* w3l = (bf*)alloc((size_t)DLAT * DH2 * 2);
    bf* w4h = (bf*)alloc((size_t)DH2 * DLAT * 2);  bf* w4l = (bf*)alloc((size_t)DH2 * DLAT * 2);
    bf* w5h = (bf*)alloc((size_t)DH1 * DH2 * 2);   bf* w5l = (bf*)alloc((size_t)DH1 * DH2 * 2);
    bf* w6h = (bf*)alloc((size_t)D0 * DH1 * 2);    bf* w6l = (bf*)alloc((size_t)D0 * DH1 * 2);
    bf* h1h = (bf*)alloc((size_t)NROW * DH1 * 2);  bf* h1l = (bf*)alloc((size_t)NROW * DH1 * 2);
    bf* h2h = (bf*)alloc((size_t)NROW * DH2 * 2);  bf* h2l = (bf*)alloc((size_t)NROW * DH2 * 2);
    bf* lth = (bf*)alloc((size_t)NROW * DLAT * 2); bf* ltl = (bf*)alloc((size_t)NROW * DLAT * 2);
    bf* d4h = (bf*)alloc((size_t)NROW * DH2 * 2);  bf* d4l = (bf*)alloc((size_t)NROW * DH2 * 2);
    bf* d5h = (bf*)alloc((size_t)NROW * DH1 * 2);  bf* d5l = (bf*)alloc((size_t)NROW * DH1 * 2);
    float* r1v = (float*)alloc((size_t)NROW * 4);
    float* r2v = (float*)alloc((size_t)NROW * 4);      // 16384 B, 256-aligned
    double* stats = (double*)alloc(5 * 8);             // contiguous after r2v
    unsigned* d1buf = (unsigned*)alloc((size_t)528 * 8192 * 4);   // 17.3 MB packed d1

    // zero r2v + stats in one async memset (graph-capture safe)
    hipMemsetAsync(r2v, 0, (size_t)NROW * 4 + 256, stream);

    SplitArgs SA;
    const float* srcs[7] = { x, We1, We2, We3, Wd1, Wd2, Wd3 };
    bf* his[7] = { xh, w1h, w2h, w3h, w4h, w5h, w6h };
    bf* los[7] = { xl, w1l, w2l, w3l, w4l, w5l, w6l };
    unsigned ns[7] = { NROW * D0, DH1 * D0, DH2 * DH1, DLAT * DH2,
                       DH2 * DLAT, DH1 * DH2, D0 * DH1 };
    unsigned cum = 0;
    for (int i = 0; i < 7; ++i) {
        SA.s[i].src = srcs[i]; SA.s[i].hi = his[i]; SA.s[i].lo = los[i];
        SA.cum4[i] = cum; cum += ns[i] / 4;
    }
    SA.cum4[7] = cum;
    split_many<<<(cum + 255) / 256, 256, 0, stream>>>(SA, (int)cum, r1v);

    // X-distance statistics (only needs xh, r1v) — runs before the MLP chain
    pair_x<<<dim3(528), 256, 0, stream>>>(xh, r1v, d1buf, stats);

    // encoder (BM=64 tiles: grids 512 / 256 / 128 blocks)
    gemm_lrelu<<<dim3(NROW / 64, DH1 / 64), 256, 0, stream>>>(
        xh, xl, w1h, w1l, be1, nullptr, h1h, h1l, nullptr, DH1, D0);
    gemm_lrelu<<<dim3(NROW / 64, DH2 / 64), 256, 0, stream>>>(
        h1h, h1l, w2h, w2l, be2, nullptr, h2h, h2l, nullptr, DH2, DH1);
    gemm_lrelu<<<dim3(NROW / 64, DLAT / 64), 256, 0, stream>>>(
        h2h, h2l, w3h, w3l, be3, nullptr, lth, ltl, r2v, DLAT, DH2);
    // decoder (grids 256 / 512 / 1024 blocks)
    gemm_lrelu<<<dim3(NROW / 64, DH2 / 64), 256, 0, stream>>>(
        lth, ltl, w4h, w4l, bd1, nullptr, d4h, d4l, nullptr, DH2, DLAT);
    gemm_lrelu<<<dim3(NROW / 64, DH1 / 64), 256, 0, stream>>>(
        d4h, d4l, w5h, w5l, bd2, nullptr, d5h, d5l, nullptr, DH1, DH2);
    gemm_lrelu<<<dim3(NROW / 64, D0 / 64), 256, 0, stream>>>(
        d5h, d5l, w6h, w6l, bd3, out, nullptr, nullptr, nullptr, D0, DH1);

    // latent-distance statistics + cross term
    pair_l<<<dim3(528), 256, 0, stream>>>(lth, r2v, d1buf, stats);
    finalize_corr<<<1, 1, 0, stream>>>(stats, out + (size_t)NROW * D0);
}